// Round 6
// baseline (327.899 us; speedup 1.0000x reference)
//
#include <hip/hip_runtime.h>
#include <hip/hip_bf16.h>

using bf16 = __hip_bfloat16;
typedef __attribute__((ext_vector_type(4))) float f32x4;
typedef __attribute__((ext_vector_type(8))) short short8;
typedef __attribute__((ext_vector_type(2))) unsigned int uint2v;
typedef __attribute__((ext_vector_type(4))) unsigned int uint4v;

#define DEVI static __device__ __forceinline__

DEVI unsigned short f2b(float f){
  unsigned int u = __float_as_uint(f);
  unsigned int r = (u + 0x7fffu + ((u >> 16) & 1u)) >> 16;
  return (unsigned short)r;
}
DEVI float b2f(unsigned short u){
  return __uint_as_float(((unsigned int)u) << 16);
}

DEVI void gload16(const void* g, void* l){
  __builtin_amdgcn_global_load_lds(
      (const __attribute__((address_space(1))) unsigned int*)g,
      (__attribute__((address_space(3))) unsigned int*)l, 16, 0, 0);
}

// ---- x [16][256][4096] f32 -> xT [16][4098][256] bf16 (row lp = l+1) ----
__global__ __launch_bounds__(256) void k_transpose_x(const float* __restrict__ x,
                                                     bf16* __restrict__ xt)
{
  __shared__ float tile[64][65];
  const int b = blockIdx.z, l0 = blockIdx.x*64, c0 = blockIdx.y*64;
  const int tid = threadIdx.x;
  {
    const int r = tid >> 2, q = tid & 3;
    const float* src = x + ((size_t)(b*256 + c0 + r))*4096 + l0 + q*16;
    #pragma unroll
    for (int j = 0; j < 4; ++j){
      const f32x4 v = *reinterpret_cast<const f32x4*>(src + j*4);
      #pragma unroll
      for (int e = 0; e < 4; ++e) tile[r][q*16 + j*4 + e] = v[e];
    }
  }
  __syncthreads();
  {
    const int jr = tid >> 2, cq = tid & 3;
    unsigned int w[8];
    #pragma unroll
    for (int e = 0; e < 8; ++e){
      const float lo = tile[cq*16 + 2*e][jr];
      const float hi = tile[cq*16 + 2*e + 1][jr];
      w[e] = (unsigned int)f2b(lo) | ((unsigned int)f2b(hi) << 16);
    }
    unsigned short* dst = (unsigned short*)xt + ((size_t)b*4098 + l0 + jr + 1)*256 + c0 + cq*16;
    uint4v a0 = {w[0],w[1],w[2],w[3]}, a1 = {w[4],w[5],w[6],w[7]};
    *reinterpret_cast<uint4v*>(dst)     = a0;
    *reinterpret_cast<uint4v*>(dst + 8) = a1;
  }
}

// ---- zero pad rows (lp=0 and lp=4097) of xT and h1T ----
__global__ void k_zero_pads(bf16* __restrict__ xt, bf16* __restrict__ h1t)
{
  const int b = blockIdx.x, tid = threadIdx.x;
  const size_t top = (size_t)b*4098*256 + tid;
  const size_t bot = (size_t)b*4098*256 + (size_t)4097*256 + tid;
  unsigned short* px = (unsigned short*)xt;
  unsigned short* ph = (unsigned short*)h1t;
  px[top] = 0; px[bot] = 0; ph[top] = 0; ph[bot] = 0;
}

// ---- f32 -> bf16 convert for 3 equally-sized tensors packed into dst (wb only now) ----
__global__ __launch_bounds__(256) void k_cvt3(const float* __restrict__ s0, const float* __restrict__ s1,
                                              const float* __restrict__ s2, bf16* __restrict__ dst, int n1)
{
  const size_t total = (size_t)3 * (size_t)n1 / 4;
  for (size_t i = (size_t)blockIdx.x*256 + threadIdx.x; i < total; i += (size_t)gridDim.x*256){
    const size_t e = i*4;
    const int which = (int)(e / (size_t)n1);
    const size_t off = e - (size_t)which*(size_t)n1;
    const float* s = which==0 ? s0 : which==1 ? s1 : s2;
    const f32x4 v = *reinterpret_cast<const f32x4*>(s + off);
    uint2v p;
    p[0] = (unsigned)f2b(v[0]) | ((unsigned)f2b(v[1])<<16);
    p[1] = (unsigned)f2b(v[2]) | ((unsigned)f2b(v[3])<<16);
    *reinterpret_cast<uint2v*>((unsigned short*)dst + e) = p;
  }
}

// ============================================================================
// k_gen: Wt[i][bb][t][o][c] = sum_h wb_i[c*3+t][h] * att_i[bo][h] + bias.
// 256x256 tile, BK=32, 8 waves (2M x 4N), 2-barrier counted-vmcnt skeleton.
// A (wb bf16) staged via gload_lds (dbuf); B (att) read DIRECTLY as f32 to
// regs, converted, ds_written swizzled (kills the 301 MB att cvt3 pre-pass).
// LDS 64 KB: bufA 2x16KB @0, bufB 2x16KB @32KB; epilogue C-half overlays.
// ============================================================================
__global__ __launch_bounds__(512, 2) void k_gen(const float* __restrict__ att1f, const float* __restrict__ att2f,
                                                const float* __restrict__ att3f, const bf16* __restrict__ wbp,
                                                const float* __restrict__ bias0, const float* __restrict__ bias1,
                                                const float* __restrict__ bias2, bf16* __restrict__ Wt)
{
  __shared__ bf16 sAll[32768];   // 64 KB
  // XCD swizzle: co-locate the 3 tap-blocks sharing one att tile on one XCD.
  const int flat = blockIdx.x + (blockIdx.z << 4);
  const int xcd = flat & 7, s = flat >> 3;          // s in [0,18)
  const int t = s % 3, tau = (s/3)*8 + xcd;         // tau in [0,48)
  const int i = tau >> 4, bo = tau & 15;
  const int bo0 = bo*256;
  const bf16*  __restrict__ A  = wbp + (size_t)i*768*1024 + (size_t)t*1024;
  const float* __restrict__ Bf = ((i==0) ? att1f : (i==1) ? att2f : att3f) + (size_t)bo0*1024;
  const float* __restrict__ bias = (i==0) ? bias0 : (i==1) ? bias1 : bias2;
  const int tid = threadIdx.x, lane = tid & 63, wid = tid >> 6;
  const int wr = wid >> 2, wc = wid & 3;
  const int frow = lane & 15, g = lane >> 4;
  f32x4 acc[8][4] = {};
  f32x4 rN[4];

  const int rB = tid >> 1, hB = tid & 1;            // B reg-stage: row, col-half
  const float* bsBase = Bf + (size_t)rB*1024 + hB*16;

#define GEN_STAGE_A(kt, bufi) { \
    _Pragma("unroll") \
    for (int j = 0; j < 2; ++j){ \
      const int q = tid + j*512, r = q >> 2, s3 = q & 3; \
      const int cc = (s3 ^ ((r >> 1) & 3)) * 8; \
      gload16(A + (size_t)r*3072 + (kt)*32 + cc, &sAll[(bufi)*8192 + q*8]); \
    } }

#define GEN_WRITE_B(bufi) { \
    unsigned short* wp = (unsigned short*)&sAll[16384 + (bufi)*8192]; \
    uint4v w0, w1; \
    w0[0] = (unsigned)f2b(rN[0][0]) | ((unsigned)f2b(rN[0][1])<<16); \
    w0[1] = (unsigned)f2b(rN[0][2]) | ((unsigned)f2b(rN[0][3])<<16); \
    w0[2] = (unsigned)f2b(rN[1][0]) | ((unsigned)f2b(rN[1][1])<<16); \
    w0[3] = (unsigned)f2b(rN[1][2]) | ((unsigned)f2b(rN[1][3])<<16); \
    w1[0] = (unsigned)f2b(rN[2][0]) | ((unsigned)f2b(rN[2][1])<<16); \
    w1[1] = (unsigned)f2b(rN[2][2]) | ((unsigned)f2b(rN[2][3])<<16); \
    w1[2] = (unsigned)f2b(rN[3][0]) | ((unsigned)f2b(rN[3][1])<<16); \
    w1[3] = (unsigned)f2b(rN[3][2]) | ((unsigned)f2b(rN[3][3])<<16); \
    const int sl0 = (hB*2 + 0) ^ ((rB >> 1) & 3); \
    const int sl1 = (hB*2 + 1) ^ ((rB >> 1) & 3); \
    *reinterpret_cast<uint4v*>(wp + rB*32 + sl0*8) = w0; \
    *reinterpret_cast<uint4v*>(wp + rB*32 + sl1*8) = w1; }

  // prologue: B(0) -> regs, A(0) -> LDS; publish both.
  #pragma unroll
  for (int q = 0; q < 4; ++q) rN[q] = *reinterpret_cast<const f32x4*>(bsBase + q*4);
  GEN_STAGE_A(0, 0);
  asm volatile("s_waitcnt vmcnt(0)" ::: "memory");
  GEN_WRITE_B(0);
  asm volatile("s_waitcnt lgkmcnt(0)" ::: "memory");
  __builtin_amdgcn_s_barrier();

  #pragma unroll 1
  for (int kt = 0; kt < 32; ++kt){
    const int p = kt & 1;
    if (kt + 1 < 32){
      #pragma unroll
      for (int q = 0; q < 4; ++q) rN[q] = *reinterpret_cast<const f32x4*>(bsBase + (kt+1)*32 + q*4);
      GEN_STAGE_A(kt+1, p^1);
      asm volatile("s_waitcnt vmcnt(6)" ::: "memory");   // all but this iter's 6 -> A(kt) landed
    } else {
      asm volatile("s_waitcnt vmcnt(0)" ::: "memory");
    }
    __builtin_amdgcn_s_barrier();
    const bf16* pA = sAll + p*8192;
    const bf16* pB = sAll + 16384 + p*8192;
    short8 bfr[4];
    #pragma unroll
    for (int n = 0; n < 4; ++n){
      const int row = wc*64 + n*16 + frow;
      const int sl = g ^ ((row >> 1) & 3);
      bfr[n] = *reinterpret_cast<const short8*>(pB + row*32 + sl*8);
    }
    __builtin_amdgcn_s_setprio(1);
    #pragma unroll
    for (int m = 0; m < 8; ++m){
      const int row = wr*128 + m*16 + frow;
      const int sl = g ^ ((row >> 1) & 3);
      const short8 af = *reinterpret_cast<const short8*>(pA + row*32 + sl*8);
      #pragma unroll
      for (int n = 0; n < 4; ++n)
        acc[m][n] = __builtin_amdgcn_mfma_f32_16x16x32_bf16(af, bfr[n], acc[m][n], 0, 0, 0);
    }
    __builtin_amdgcn_s_setprio(0);
    if (kt + 1 < 32){
      GEN_WRITE_B(p^1);          // compiler waits the rN f32 loads itself
    }
    asm volatile("s_waitcnt lgkmcnt(0)" ::: "memory");
    __builtin_amdgcn_s_barrier();
  }
#undef GEN_STAGE_A
#undef GEN_WRITE_B

  // epilogue: two passes (C-tile 256x256 = 128 KB > 64 KB LDS).
  // C row = bo (wc side), col = c (wr side). Pass 0: wc<2 (rows 0..127).
  char* gp = (char*)Wt + 2*(((size_t)(i*16 + bo)*3 + t)*65536);
  #pragma unroll
  for (int pass = 0; pass < 2; ++pass){
    if ((wc >> 1) == pass){
      #pragma unroll
      for (int m = 0; m < 8; ++m){
        const int col = wr*128 + m*16 + g*4;
        float bi[4];
        #pragma unroll
        for (int j = 0; j < 4; ++j) bi[j] = bias[(col + j)*3 + t];
        #pragma unroll
        for (int n = 0; n < 4; ++n){
          const int row = wc*64 + n*16 + frow;
          const int lrow = row & 127;
          uint2v pk;
          pk[0] = (unsigned)f2b(acc[m][n][0] + bi[0]) | ((unsigned)f2b(acc[m][n][1] + bi[1]) << 16);
          pk[1] = (unsigned)f2b(acc[m][n][2] + bi[2]) | ((unsigned)f2b(acc[m][n][3] + bi[3]) << 16);
          const int chunk = (col >> 3) ^ (lrow & 31);
          *reinterpret_cast<uint2v*>((char*)sAll + lrow*512 + chunk*16 + (g&1)*8) = pk;
        }
      }
    }
    __syncthreads();
    #pragma unroll
    for (int it = 0; it < 8; ++it){
      const int lrow = it*16 + (tid >> 5);
      const int c = tid & 31;
      const int cs2 = c ^ (lrow & 31);
      const uint4v v = *reinterpret_cast<const uint4v*>((const char*)sAll + lrow*512 + cs2*16);
      *reinterpret_cast<uint4v*>(gp + (size_t)(pass*128 + lrow)*512 + c*16) = v;
    }
    __syncthreads();
  }
}

// ---- b1[b*256+o] = att1[bo,:] . b1_w + b1_b ----
__global__ __launch_bounds__(256) void k_b1(const float* __restrict__ att1, const float* __restrict__ b1w,
                                            const float* __restrict__ b1b, float* __restrict__ out)
{
  const int m = blockIdx.x*4 + (threadIdx.x >> 6);
  const int lane = threadIdx.x & 63;
  const float* a = att1 + (size_t)m*1024;
  float s = 0.f;
  for (int k = lane*4; k < 1024; k += 256){
    const f32x4 v = *reinterpret_cast<const f32x4*>(a + k);
    const f32x4 w = *reinterpret_cast<const f32x4*>(b1w + k);
    s += v[0]*w[0] + v[1]*w[1] + v[2]*w[2] + v[3]*w[3];
  }
  #pragma unroll
  for (int d = 32; d > 0; d >>= 1) s += __shfl_down(s, d);
  if (lane == 0) out[m] = s + b1b[0];
}

// ============================================================================
// k_conv: out[b][l][o](+rowOff) = sum_t sum_c W[b][t][o][c] * Xt[b][l+t][c].
// Tile BM=256 (o, all) x BN=128 (l), BK=32, 24 K-steps (tap-inner order).
// 8 waves = 4M x 2N; per-wave 64x64 out (acc 64 VGPR) -> 2 blocks/CU
// (__launch_bounds__(512,4), 64 KB LDS). Same counted-vmcnt 2-barrier loop.
// ============================================================================
__global__ __launch_bounds__(512, 4) void k_conv(const bf16* __restrict__ Xt, const bf16* __restrict__ W,
                                                 const float* __restrict__ bias, bf16* __restrict__ out,
                                                 int outBatchStride, int outRowOff, int applyRelu,
                                                 float* __restrict__ statSum, float* __restrict__ statSq)
{
  __shared__ bf16 sAll[32768];   // 64 KB: A dbuf 2x16KB @0, B dbuf 2x8KB @32KB; C-tile overlay
  const int flat = blockIdx.x + (blockIdx.z << 5);  // [0,512)
  const int xcd = flat & 7, slot = flat >> 3;       // slot in [0,64)
  const int b = 2*xcd + (slot >> 5);
  const int l0 = (slot & 31) * 128;
  const int tid = threadIdx.x, lane = tid & 63, wid = tid >> 6;
  const int wr = wid >> 1, wc = wid & 1;            // 4 M-waves x 2 N-waves
  const int frow = lane & 15, g = lane >> 4;
  f32x4 acc[4][4] = {};

#define CONV_STAGE(kt, bufi) { \
    const int ct3 = (kt)/3, tt = (kt) - ct3*3, c0 = ct3*32; \
    const bf16* Ab = W  + (((size_t)b*3 + tt)*256)*256 + c0; \
    const bf16* Bb = Xt + ((size_t)b*4098 + l0 + tt)*256 + c0; \
    _Pragma("unroll") \
    for (int j = 0; j < 2; ++j){ \
      const int q = tid + j*512, r = q >> 2, s3 = q & 3; \
      const int cc = (s3 ^ ((r >> 1) & 3)) * 8; \
      gload16(Ab + (size_t)r*256 + cc, &sAll[(bufi)*8192 + q*8]); \
    } \
    { const int q = tid, r = q >> 2, s3 = q & 3; \
      const int cc = (s3 ^ ((r >> 1) & 3)) * 8; \
      gload16(Bb + (size_t)r*256 + cc, &sAll[16384 + (bufi)*4096 + q*8]); } \
  }

  CONV_STAGE(0, 0);
  #pragma unroll 1
  for (int kt = 0; kt < 24; ++kt){
    const int buf = kt & 1;
    if (kt + 1 < 24){
      CONV_STAGE(kt+1, buf^1);
      asm volatile("s_waitcnt vmcnt(3)" ::: "memory");   // all but this iter's 3 -> kt landed
    } else {
      asm volatile("s_waitcnt vmcnt(0)" ::: "memory");
    }
    __builtin_amdgcn_s_barrier();
    const bf16* pA = sAll + buf*8192;
    const bf16* pB = sAll + 16384 + buf*4096;
    short8 bfr[4], afr[4];
    #pragma unroll
    for (int n = 0; n < 4; ++n){
      const int row = wc*64 + n*16 + frow;               // l in [0,128)
      const int sl = g ^ ((row >> 1) & 3);
      bfr[n] = *reinterpret_cast<const short8*>(pB + row*32 + sl*8);
    }
    #pragma unroll
    for (int m = 0; m < 4; ++m){
      const int row = wr*64 + m*16 + frow;               // o in [0,256)
      const int sl = g ^ ((row >> 1) & 3);
      afr[m] = *reinterpret_cast<const short8*>(pA + row*32 + sl*8);
    }
    __builtin_amdgcn_s_setprio(1);
    #pragma unroll
    for (int m = 0; m < 4; ++m)
      #pragma unroll
      for (int n = 0; n < 4; ++n)
        acc[m][n] = __builtin_amdgcn_mfma_f32_16x16x32_bf16(afr[m], bfr[n], acc[m][n], 0, 0, 0);
    __builtin_amdgcn_s_setprio(0);
    __builtin_amdgcn_s_barrier();
  }
#undef CONV_STAGE

  // epilogue: bias/relu/stats; acc -> swizzled LDS C-tile [128 l][256 o];
  // full-line 512 B coalesced blast (no partial-line L2 write-allocate).
  float cs[4][4] = {{0.f}}, cq[4][4] = {{0.f}};
  #pragma unroll
  for (int m = 0; m < 4; ++m){
    const int col = wr*64 + m*16 + g*4;                  // output channel o
    float bi[4] = {0.f, 0.f, 0.f, 0.f};
    if (bias){
      const f32x4 bv = *reinterpret_cast<const f32x4*>(bias + b*256 + col);
      bi[0]=bv[0]; bi[1]=bv[1]; bi[2]=bv[2]; bi[3]=bv[3];
    }
    #pragma unroll
    for (int n = 0; n < 4; ++n){
      const int row = wc*64 + n*16 + frow;               // l in [0,128)
      float v[4];
      #pragma unroll
      for (int j = 0; j < 4; ++j){
        v[j] = acc[m][n][j] + bi[j];
        if (applyRelu) v[j] = fmaxf(v[j], 0.f);
        cs[m][j] += v[j];
        cq[m][j] += v[j]*v[j];
      }
      uint2v pk;
      pk[0] = (unsigned)f2b(v[0]) | ((unsigned)f2b(v[1]) << 16);
      pk[1] = (unsigned)f2b(v[2]) | ((unsigned)f2b(v[3]) << 16);
      const int chunk = (col >> 3) ^ (row & 31);
      *reinterpret_cast<uint2v*>((char*)sAll + row*512 + chunk*16 + (g&1)*8) = pk;
    }
  }
  __syncthreads();
  {
    char* gp = (char*)out + 2*((size_t)b*outBatchStride + (size_t)(l0 + outRowOff)*256);
    #pragma unroll
    for (int it = 0; it < 8; ++it){
      const int row = it*16 + (tid >> 5);
      const int c = tid & 31;
      const int cs2 = c ^ (row & 31);
      const uint4v v = *reinterpret_cast<const uint4v*>((const char*)sAll + row*512 + cs2*16);
      *reinterpret_cast<uint4v*>(gp + (size_t)row*512 + c*16) = v;
    }
  }
  if (statSum){
    #pragma unroll
    for (int m = 0; m < 4; ++m)
      #pragma unroll
      for (int j = 0; j < 4; ++j){
        #pragma unroll
        for (int d = 1; d < 16; d <<= 1){
          cs[m][j] += __shfl_xor(cs[m][j], d);
          cq[m][j] += __shfl_xor(cq[m][j], d);
        }
      }
    __syncthreads();                       // blast reads done -> LDS reusable
    float* ls = (float*)sAll;              // [8 waves][64 ch]
    float* lq = ls + 512;
    if (frow == 0){
      #pragma unroll
      for (int m = 0; m < 4; ++m)
        #pragma unroll
        for (int j = 0; j < 4; ++j){
          ls[wid*64 + m*16 + g*4 + j] = cs[m][j];
          lq[wid*64 + m*16 + g*4 + j] = cq[m][j];
        }
    }
    __syncthreads();
    if (tid < 256){
      const int o = tid, wrI = o >> 6, idx = o & 63;
      const float s  = ls[(wrI*2 + 0)*64 + idx] + ls[(wrI*2 + 1)*64 + idx];
      const float qq = lq[(wrI*2 + 0)*64 + idx] + lq[(wrI*2 + 1)*64 + idx];
      atomicAdd(statSum + o, s);
      atomicAdd(statSq  + o, qq);
    }
  }
}

__global__ void k_bnfin(const float* __restrict__ sum, const float* __restrict__ sq,
                        const float* __restrict__ g, const float* __restrict__ bb,
                        float* __restrict__ scale, float* __restrict__ shift)
{
  const int o = threadIdx.x;
  const float inv = 1.f/65536.f;
  const float m = sum[o]*inv;
  const float v = fmaxf(sq[o]*inv - m*m, 0.f);
  const float sc = g[o] / sqrtf(v + 1e-5f);
  scale[o] = sc;
  shift[o] = bb[o] - m*sc;
}

// ---- h2T[b][lp][o] = relu(y2T[b][lp-1][o]*scale+shift), pads zeroed ----
__global__ __launch_bounds__(256) void k_norm2(const bf16* __restrict__ y, const float* __restrict__ scale,
                                               const float* __restrict__ shift, bf16* __restrict__ h)
{
  const int gr = blockIdx.x*8 + (threadIdx.x >> 5);
  const int oc = threadIdx.x & 31;
  const int b = gr / 4098, lp = gr - b*4098;
  unsigned short* dst = (unsigned short*)h + (size_t)gr*256 + oc*8;
  if (lp == 0 || lp == 4097){
    uint4v z = {0u,0u,0u,0u};
    *reinterpret_cast<uint4v*>(dst) = z;
    return;
  }
  const unsigned short* src = (const unsigned short*)y + ((size_t)b*4096 + (lp-1))*256 + oc*8;
  const uint4v in = *reinterpret_cast<const uint4v*>(src);
  const f32x4 sA0 = *reinterpret_cast<const f32x4*>(scale + oc*8);
  const f32x4 sA1 = *reinterpret_cast<const f32x4*>(scale + oc*8 + 4);
  const f32x4 hA0 = *reinterpret_cast<const f32x4*>(shift + oc*8);
  const f32x4 hA1 = *reinterpret_cast<const f32x4*>(shift + oc*8 + 4);
  uint4v ov;
  #pragma unroll
  for (int e = 0; e < 4; ++e){
    const unsigned int w = in[e];
    const float sc0 = (e<2) ? sA0[2*e] : sA1[2*e-4];
    const float sc1 = (e<2) ? sA0[2*e+1] : sA1[2*e-3];
    const float sh0 = (e<2) ? hA0[2*e] : hA1[2*e-4];
    const float sh1 = (e<2) ? hA0[2*e+1] : hA1[2*e-3];
    const float v0 = fmaxf(b2f((unsigned short)(w & 0xffffu))*sc0 + sh0, 0.f);
    const float v1 = fmaxf(b2f((unsigned short)(w >> 16))*sc1 + sh1, 0.f);
    ov[e] = (unsigned)f2b(v0) | ((unsigned)f2b(v1) << 16);
  }
  *reinterpret_cast<uint4v*>(dst) = ov;
}

// ---- h3 = relu(y3*scale+shift) in-place, plus per-(b,o) sums for SE ----
__global__ __launch_bounds__(256) void k_norm3(bf16* __restrict__ y, const float* __restrict__ scale,
                                               const float* __restrict__ shift, float* __restrict__ s_sum)
{
  __shared__ float red[8][256];
  const int tid = threadIdx.x;
  const int rr = tid >> 5, oc = tid & 31;
  const size_t row = (size_t)blockIdx.x*8 + rr;
  const int b = (int)(row >> 12);
  unsigned short* p = (unsigned short*)y + row*256 + oc*8;
  const uint4v in = *reinterpret_cast<const uint4v*>(p);
  const f32x4 sA0 = *reinterpret_cast<const f32x4*>(scale + oc*8);
  const f32x4 sA1 = *reinterpret_cast<const f32x4*>(scale + oc*8 + 4);
  const f32x4 hA0 = *reinterpret_cast<const f32x4*>(shift + oc*8);
  const f32x4 hA1 = *reinterpret_cast<const f32x4*>(shift + oc*8 + 4);
  uint4v ov;
  float loc[8];
  #pragma unroll
  for (int e = 0; e < 4; ++e){
    const unsigned int w = in[e];
    const float sc0 = (e<2) ? sA0[2*e] : sA1[2*e-4];
    const float sc1 = (e<2) ? sA0[2*e+1] : sA1[2*e-3];
    const float sh0 = (e<2) ? hA0[2*e] : hA1[2*e-4];
    const float sh1 = (e<2) ? hA0[2*e+1] : hA1[2*e-3];
    const float v0 = fmaxf(b2f((unsigned short)(w & 0xffffu))*sc0 + sh0, 0.f);
    const float v1 = fmaxf(b2f((unsigned short)(w >> 16))*sc1 + sh1, 0.f);
    loc[2*e] = v0; loc[2*e+1] = v1;
    ov[e] = (unsigned)f2b(v0) | ((unsigned)f2b(v1) << 16);
  }
  *reinterpret_cast<uint4v*>(p) = ov;
  #pragma unroll
  for (int j = 0; j < 8; ++j) red[rr][oc*8 + j] = loc[j];
  __syncthreads();
  const int o = tid;
  float tot = 0.f;
  #pragma unroll
  for (int r2 = 0; r2 < 8; ++r2) tot += red[r2][o];
  atomicAdd(&s_sum[(size_t)b*256 + o], tot);
}

// ---- SE: s2[b][o] = sigmoid(W2 @ relu(W1 @ mean + b1) + b2) ----
__global__ __launch_bounds__(256) void k_se(const float* __restrict__ s_sum, const float* __restrict__ w1,
                                            const float* __restrict__ b1, const float* __restrict__ w2,
                                            const float* __restrict__ b2, float* __restrict__ s2)
{
  __shared__ float sv[256];
  __shared__ float t1[256];
  const int b = blockIdx.x, o = threadIdx.x;
  sv[o] = s_sum[(size_t)b*256 + o] * (1.f/4096.f);
  __syncthreads();
  float a = b1[o];
  for (int c = 0; c < 256; ++c) a += w1[(size_t)o*256 + c] * sv[c];
  t1[o] = fmaxf(a, 0.f);
  __syncthreads();
  float a2 = b2[o];
  for (int c = 0; c < 256; ++c) a2 += w2[(size_t)o*256 + c] * t1[c];
  s2[(size_t)b*256 + o] = 1.f / (1.f + expf(-a2));
}

// ---- out[b][o][l] = relu(h3T[b][l][o]*s2[b][o] + x[b][o][l]) ----
__global__ __launch_bounds__(256) void k_final(const bf16* __restrict__ h3, const float* __restrict__ s2,
                                               const float* __restrict__ x, float* __restrict__ out)
{
  __shared__ float tile[64][65];
  const int b = blockIdx.z, o0 = blockIdx.y*64, l0 = blockIdx.x*64;
  const int tid = threadIdx.x;
  {
    const int r = tid >> 2, q = tid & 3;
    const unsigned short* src = (const unsigned short*)h3 + ((size_t)b*4096 + l0 + r)*256 + o0 + q*16;
    const uint4v a0 = *reinterpret_cast<const uint4v*>(src);
    const uint4v a1 = *reinterpret_cast<const uint4v*>(src + 8);
    #pragma unroll
    for (int e = 0; e < 4; ++e){
      tile[r][q*16 + 2*e]         = b2f((unsigned short)(a0[e] & 0xffffu));
      tile[r][q*16 + 2*e + 1]     = b2f((unsigned short)(a0[e] >> 16));
      tile[r][q*16 + 8 + 2*e]     = b2f((unsigned short)(a1[e] & 0xffffu));
      tile[r][q*16 + 8 + 2*e + 1] = b2f((unsigned short)(a1[e] >> 16));
    }
  }
  __syncthreads();
  {
    const int orow = tid >> 2, q = tid & 3;
    const int o = o0 + orow;
    const float sc = s2[(size_t)b*256 + o];
    const float* xs = x + ((size_t)b*256 + o)*4096 + l0 + q*16;
    float* dst = out + ((size_t)b*256 + o)*4096 + l0 + q*16;
    #pragma unroll
    for (int k = 0; k < 16; k += 4){
      const f32x4 xv = *reinterpret_cast<const f32x4*>(xs + k);
      f32x4 r;
      #pragma unroll
      for (int e = 0; e < 4; ++e)
        r[e] = fmaxf(tile[q*16 + k + e][orow]*sc + xv[e], 0.f);
      *reinterpret_cast<f32x4*>(dst + k) = r;
    }
  }
}

extern "C" void kernel_launch(void* const* d_in, const int* in_sizes, int n_in,
                              void* d_out, int out_size, void* d_ws, size_t ws_size,
                              hipStream_t stream)
{
  const float* x     = (const float*)d_in[0];
  const float* att1  = (const float*)d_in[1];
  const float* att2  = (const float*)d_in[2];
  const float* att3  = (const float*)d_in[3];
  const float* w1_w  = (const float*)d_in[4];
  const float* w1_b  = (const float*)d_in[5];
  const float* w2_w  = (const float*)d_in[6];
  const float* w2_b  = (const float*)d_in[7];
  const float* w3_w  = (const float*)d_in[8];
  const float* w3_b  = (const float*)d_in[9];
  const float* b1_w  = (const float*)d_in[10];
  const float* b1_b  = (const float*)d_in[11];
  const float* bn2_w = (const float*)d_in[12];
  const float* bn2_b = (const float*)d_in[13];
  const float* bn3_w = (const float*)d_in[14];
  const float* bn3_b = (const float*)d_in[15];
  const float* se1_w = (const float*)d_in[16];
  const float* se1_b = (const float*)d_in[17];
  const float* se2_w = (const float*)d_in[18];
  const float* se2_b = (const float*)d_in[19];

  char* ws = (char*)d_ws;
  // workspace layout (bytes)
  bf16*  xT   = (bf16*)(ws + 0);           // [16][4098][256]  (reused as y3T/h3T)
  bf16*  h1T  = (bf16*)(ws + 33570816);    // [16][4098][256]
  bf16*  y2T  = (bf16*)(ws + 67141632);    // [16][4096][256]
  bf16*  h2T  = (bf16*)(ws + 100696064);   // [16][4098][256]
  bf16*  Wt   = (bf16*)(ws + 134266880);   // [3][16][3][256][256]
  bf16*  wb   = (bf16*)(ws + 178307072);   // [3][768][1024]
  float* b1v  = (float*)(ws + 183025664);  // [4096]
  float* st   = (float*)(ws + 183042048);
  float* bn2sum = st;          // 256
  float* bn2sq  = st + 256;
  float* bn3sum = st + 512;
  float* bn3sq  = st + 768;
  float* s_sum  = st + 1024;   // 4096
  float* scale2 = st + 5120;
  float* shift2 = st + 5376;
  float* scale3 = st + 5632;
  float* shift3 = st + 5888;
  float* s2v    = st + 6144;   // 4096
  bf16*  y3T  = (bf16*)(ws + 0);           // overlay on xT (dead after conv1)

  // zero accumulators (bn2/bn3 sums + s_sum = 5120 floats)
  hipMemsetAsync(st, 0, 5120*sizeof(float), stream);

  k_transpose_x<<<dim3(64,4,16),256,0,stream>>>(x, xT);
  k_zero_pads<<<16,256,0,stream>>>(xT, h1T);
  k_cvt3<<<512,256,0,stream>>>(w1_w, w2_w, w3_w, wb, 768*1024);
  k_gen<<<dim3(16,1,9),512,0,stream>>>(att1, att2, att3, wb, w1_b, w2_b, w3_b, Wt);
  k_b1<<<1024,256,0,stream>>>(att1, b1_w, b1_b, b1v);

  k_conv<<<dim3(32,1,16),512,0,stream>>>(xT,  Wt,                           b1v,     h1T, 4098*256, 1, 1, nullptr, nullptr);
  k_conv<<<dim3(32,1,16),512,0,stream>>>(h1T, Wt + (size_t)1*16*3*256*256,  nullptr, y2T, 4096*256, 0, 0, bn2sum, bn2sq);
  k_bnfin<<<1,256,0,stream>>>(bn2sum, bn2sq, bn2_w, bn2_b, scale2, shift2);
  k_norm2<<<8196,256,0,stream>>>(y2T, scale2, shift2, h2T);
  k_conv<<<dim3(32,1,16),512,0,stream>>>(h2T, Wt + (size_t)2*16*3*256*256,  nullptr, y3T, 4096*256, 0, 0, bn3sum, bn3sq);
  k_bnfin<<<1,256,0,stream>>>(bn3sum, bn3sq, bn3_w, bn3_b, scale3, shift3);
  k_norm3<<<8192,256,0,stream>>>(y3T, scale3, shift3, s_sum);
  k_se<<<16,256,0,stream>>>(s_sum, se1_w, se1_b, se2_w, se2_b, s2v);
  k_final<<<dim3(64,4,16),256,0,stream>>>((const bf16*)y3T, s2v, x, (float*)d_out);
}

// Round 7
// 326.866 us; speedup vs baseline: 1.0032x; 1.0032x over previous
//
#include <hip/hip_runtime.h>
#include <hip/hip_bf16.h>

using bf16 = __hip_bfloat16;
typedef __attribute__((ext_vector_type(4))) float f32x4;
typedef __attribute__((ext_vector_type(8))) short short8;
typedef __attribute__((ext_vector_type(2))) unsigned int uint2v;
typedef __attribute__((ext_vector_type(4))) unsigned int uint4v;

#define DEVI static __device__ __forceinline__

DEVI unsigned short f2b(float f){
  unsigned int u = __float_as_uint(f);
  unsigned int r = (u + 0x7fffu + ((u >> 16) & 1u)) >> 16;
  return (unsigned short)r;
}
DEVI float b2f(unsigned short u){
  return __uint_as_float(((unsigned int)u) << 16);
}

DEVI void gload16(const void* g, void* l){
  __builtin_amdgcn_global_load_lds(
      (const __attribute__((address_space(1))) unsigned int*)g,
      (__attribute__((address_space(3))) unsigned int*)l, 16, 0, 0);
}

// ---- x [16][256][4096] f32 -> xT [16][4098][256] bf16 (row lp = l+1) ----
__global__ __launch_bounds__(256) void k_transpose_x(const float* __restrict__ x,
                                                     bf16* __restrict__ xt)
{
  __shared__ float tile[64][65];
  const int b = blockIdx.z, l0 = blockIdx.x*64, c0 = blockIdx.y*64;
  const int tid = threadIdx.x;
  {
    const int r = tid >> 2, q = tid & 3;
    const float* src = x + ((size_t)(b*256 + c0 + r))*4096 + l0 + q*16;
    #pragma unroll
    for (int j = 0; j < 4; ++j){
      const f32x4 v = *reinterpret_cast<const f32x4*>(src + j*4);
      #pragma unroll
      for (int e = 0; e < 4; ++e) tile[r][q*16 + j*4 + e] = v[e];
    }
  }
  __syncthreads();
  {
    const int jr = tid >> 2, cq = tid & 3;
    unsigned int w[8];
    #pragma unroll
    for (int e = 0; e < 8; ++e){
      const float lo = tile[cq*16 + 2*e][jr];
      const float hi = tile[cq*16 + 2*e + 1][jr];
      w[e] = (unsigned int)f2b(lo) | ((unsigned int)f2b(hi) << 16);
    }
    unsigned short* dst = (unsigned short*)xt + ((size_t)b*4098 + l0 + jr + 1)*256 + c0 + cq*16;
    uint4v a0 = {w[0],w[1],w[2],w[3]}, a1 = {w[4],w[5],w[6],w[7]};
    *reinterpret_cast<uint4v*>(dst)     = a0;
    *reinterpret_cast<uint4v*>(dst + 8) = a1;
  }
}

// ---- zero pad rows (lp=0 and lp=4097) of xT and h1T ----
__global__ void k_zero_pads(bf16* __restrict__ xt, bf16* __restrict__ h1t)
{
  const int b = blockIdx.x, tid = threadIdx.x;
  const size_t top = (size_t)b*4098*256 + tid;
  const size_t bot = (size_t)b*4098*256 + (size_t)4097*256 + tid;
  unsigned short* px = (unsigned short*)xt;
  unsigned short* ph = (unsigned short*)h1t;
  px[top] = 0; px[bot] = 0; ph[top] = 0; ph[bot] = 0;
}

// ---- f32 -> bf16 convert for 3 equally-sized tensors packed into dst (wb only) ----
__global__ __launch_bounds__(256) void k_cvt3(const float* __restrict__ s0, const float* __restrict__ s1,
                                              const float* __restrict__ s2, bf16* __restrict__ dst, int n1)
{
  const size_t total = (size_t)3 * (size_t)n1 / 4;
  for (size_t i = (size_t)blockIdx.x*256 + threadIdx.x; i < total; i += (size_t)gridDim.x*256){
    const size_t e = i*4;
    const int which = (int)(e / (size_t)n1);
    const size_t off = e - (size_t)which*(size_t)n1;
    const float* s = which==0 ? s0 : which==1 ? s1 : s2;
    const f32x4 v = *reinterpret_cast<const f32x4*>(s + off);
    uint2v p;
    p[0] = (unsigned)f2b(v[0]) | ((unsigned)f2b(v[1])<<16);
    p[1] = (unsigned)f2b(v[2]) | ((unsigned)f2b(v[3])<<16);
    *reinterpret_cast<uint2v*>((unsigned short*)dst + e) = p;
  }
}

// ============================================================================
// k_gen: Wt[i][bb][t][o][c] = sum_h wb_i[c*3+t][h] * att_i[bo][h] + bias.
// 256x256 tile, BK=32, 8 waves (2M x 4N), 2-barrier counted-vmcnt skeleton.
// A (wb bf16) via gload_lds dbuf; B (att) f32 -> regs -> cvt -> swizzled
// ds_write (no att pre-pass). R6 bug: vmcnt(6) drained the just-issued rN
// f32 loads -> att HBM latency serialized into every K-step. Fix: vmcnt(10)
// leaves rN(kt+1) in flight (queue: [glds(kt):6 | rN:4, glds(kt+1):6]);
// the compiler's own waitcnt before GEN_WRITE_B lands after the MFMA phase.
// ============================================================================
__global__ __launch_bounds__(512, 2) void k_gen(const float* __restrict__ att1f, const float* __restrict__ att2f,
                                                const float* __restrict__ att3f, const bf16* __restrict__ wbp,
                                                const float* __restrict__ bias0, const float* __restrict__ bias1,
                                                const float* __restrict__ bias2, bf16* __restrict__ Wt)
{
  __shared__ bf16 sAll[32768];   // 64 KB
  const int flat = blockIdx.x + (blockIdx.z << 4);
  const int xcd = flat & 7, s = flat >> 3;          // s in [0,18)
  const int t = s % 3, tau = (s/3)*8 + xcd;         // tau in [0,48)
  const int i = tau >> 4, bo = tau & 15;
  const int bo0 = bo*256;
  const bf16*  __restrict__ A  = wbp + (size_t)i*768*1024 + (size_t)t*1024;
  const float* __restrict__ Bf = ((i==0) ? att1f : (i==1) ? att2f : att3f) + (size_t)bo0*1024;
  const float* __restrict__ bias = (i==0) ? bias0 : (i==1) ? bias1 : bias2;
  const int tid = threadIdx.x, lane = tid & 63, wid = tid >> 6;
  const int wr = wid >> 2, wc = wid & 3;
  const int frow = lane & 15, g = lane >> 4;
  f32x4 acc[8][4] = {};
  f32x4 rN[4];

  const int rB = tid >> 1, hB = tid & 1;            // B reg-stage: row, col-half
  const float* bsBase = Bf + (size_t)rB*1024 + hB*16;

#define GEN_STAGE_A(kt, bufi) { \
    _Pragma("unroll") \
    for (int j = 0; j < 2; ++j){ \
      const int q = tid + j*512, r = q >> 2, s3 = q & 3; \
      const int cc = (s3 ^ ((r >> 1) & 3)) * 8; \
      gload16(A + (size_t)r*3072 + (kt)*32 + cc, &sAll[(bufi)*8192 + q*8]); \
    } }

#define GEN_WRITE_B(bufi) { \
    unsigned short* wp = (unsigned short*)&sAll[16384 + (bufi)*8192]; \
    uint4v w0, w1; \
    w0[0] = (unsigned)f2b(rN[0][0]) | ((unsigned)f2b(rN[0][1])<<16); \
    w0[1] = (unsigned)f2b(rN[0][2]) | ((unsigned)f2b(rN[0][3])<<16); \
    w0[2] = (unsigned)f2b(rN[1][0]) | ((unsigned)f2b(rN[1][1])<<16); \
    w0[3] = (unsigned)f2b(rN[1][2]) | ((unsigned)f2b(rN[1][3])<<16); \
    w1[0] = (unsigned)f2b(rN[2][0]) | ((unsigned)f2b(rN[2][1])<<16); \
    w1[1] = (unsigned)f2b(rN[2][2]) | ((unsigned)f2b(rN[2][3])<<16); \
    w1[2] = (unsigned)f2b(rN[3][0]) | ((unsigned)f2b(rN[3][1])<<16); \
    w1[3] = (unsigned)f2b(rN[3][2]) | ((unsigned)f2b(rN[3][3])<<16); \
    const int sl0 = (hB*2 + 0) ^ ((rB >> 1) & 3); \
    const int sl1 = (hB*2 + 1) ^ ((rB >> 1) & 3); \
    *reinterpret_cast<uint4v*>(wp + rB*32 + sl0*8) = w0; \
    *reinterpret_cast<uint4v*>(wp + rB*32 + sl1*8) = w1; }

  // prologue: B(0) -> regs, A(0) -> LDS; publish both.
  #pragma unroll
  for (int q = 0; q < 4; ++q) rN[q] = *reinterpret_cast<const f32x4*>(bsBase + q*4);
  GEN_STAGE_A(0, 0);
  asm volatile("s_waitcnt vmcnt(0)" ::: "memory");
  GEN_WRITE_B(0);
  asm volatile("s_waitcnt lgkmcnt(0)" ::: "memory");
  __builtin_amdgcn_s_barrier();

  #pragma unroll 1
  for (int kt = 0; kt < 32; ++kt){
    const int p = kt & 1;
    if (kt + 1 < 32){
      #pragma unroll
      for (int q = 0; q < 4; ++q) rN[q] = *reinterpret_cast<const f32x4*>(bsBase + (kt+1)*32 + q*4);
      GEN_STAGE_A(kt+1, p^1);
      // drain ONLY glds A(kt) (oldest 6); rN(kt+1) + glds(kt+1) stay in flight
      asm volatile("s_waitcnt vmcnt(10)" ::: "memory");
    } else {
      asm volatile("s_waitcnt vmcnt(0)" ::: "memory");
    }
    __builtin_amdgcn_s_barrier();
    const bf16* pA = sAll + p*8192;
    const bf16* pB = sAll + 16384 + p*8192;
    short8 bfr[4];
    #pragma unroll
    for (int n = 0; n < 4; ++n){
      const int row = wc*64 + n*16 + frow;
      const int sl = g ^ ((row >> 1) & 3);
      bfr[n] = *reinterpret_cast<const short8*>(pB + row*32 + sl*8);
    }
    __builtin_amdgcn_s_setprio(1);
    #pragma unroll
    for (int m = 0; m < 8; ++m){
      const int row = wr*128 + m*16 + frow;
      const int sl = g ^ ((row >> 1) & 3);
      const short8 af = *reinterpret_cast<const short8*>(pA + row*32 + sl*8);
      #pragma unroll
      for (int n = 0; n < 4; ++n)
        acc[m][n] = __builtin_amdgcn_mfma_f32_16x16x32_bf16(af, bfr[n], acc[m][n], 0, 0, 0);
    }
    __builtin_amdgcn_s_setprio(0);
    if (kt + 1 < 32){
      GEN_WRITE_B(p^1);          // compiler inserts the rN wait here (post-MFMA)
    }
    asm volatile("s_waitcnt lgkmcnt(0)" ::: "memory");
    __builtin_amdgcn_s_barrier();
  }
#undef GEN_STAGE_A
#undef GEN_WRITE_B

  // epilogue: two passes (C-tile 256x256 = 128 KB > 64 KB LDS).
  char* gp = (char*)Wt + 2*(((size_t)(i*16 + bo)*3 + t)*65536);
  #pragma unroll
  for (int pass = 0; pass < 2; ++pass){
    if ((wc >> 1) == pass){
      #pragma unroll
      for (int m = 0; m < 8; ++m){
        const int col = wr*128 + m*16 + g*4;
        float bi[4];
        #pragma unroll
        for (int j = 0; j < 4; ++j) bi[j] = bias[(col + j)*3 + t];
        #pragma unroll
        for (int n = 0; n < 4; ++n){
          const int row = wc*64 + n*16 + frow;
          const int lrow = row & 127;
          uint2v pk;
          pk[0] = (unsigned)f2b(acc[m][n][0] + bi[0]) | ((unsigned)f2b(acc[m][n][1] + bi[1]) << 16);
          pk[1] = (unsigned)f2b(acc[m][n][2] + bi[2]) | ((unsigned)f2b(acc[m][n][3] + bi[3]) << 16);
          const int chunk = (col >> 3) ^ (lrow & 31);
          *reinterpret_cast<uint2v*>((char*)sAll + lrow*512 + chunk*16 + (g&1)*8) = pk;
        }
      }
    }
    __syncthreads();
    #pragma unroll
    for (int it = 0; it < 8; ++it){
      const int lrow = it*16 + (tid >> 5);
      const int c = tid & 31;
      const int cs2 = c ^ (lrow & 31);
      const uint4v v = *reinterpret_cast<const uint4v*>((const char*)sAll + lrow*512 + cs2*16);
      *reinterpret_cast<uint4v*>(gp + (size_t)(pass*128 + lrow)*512 + c*16) = v;
    }
    __syncthreads();
  }
}

// ---- b1[b*256+o] = att1[bo,:] . b1_w + b1_b ----
__global__ __launch_bounds__(256) void k_b1(const float* __restrict__ att1, const float* __restrict__ b1w,
                                            const float* __restrict__ b1b, float* __restrict__ out)
{
  const int m = blockIdx.x*4 + (threadIdx.x >> 6);
  const int lane = threadIdx.x & 63;
  const float* a = att1 + (size_t)m*1024;
  float s = 0.f;
  for (int k = lane*4; k < 1024; k += 256){
    const f32x4 v = *reinterpret_cast<const f32x4*>(a + k);
    const f32x4 w = *reinterpret_cast<const f32x4*>(b1w + k);
    s += v[0]*w[0] + v[1]*w[1] + v[2]*w[2] + v[3]*w[3];
  }
  #pragma unroll
  for (int d = 32; d > 0; d >>= 1) s += __shfl_down(s, d);
  if (lane == 0) out[m] = s + b1b[0];
}

// ============================================================================
// k_conv: out[b][l][o](+rowOff) = sum_t sum_c W[b][t][o][c] * Xt[b][l+t][c].
// Tile BM=256 (o) x BN=128 (l), BK=32, 24 K-steps (tap-inner); 8 waves =
// 4M x 2N, per-wave 64x64 -> 2 blocks/CU. Counted-vmcnt 2-barrier loop.
// ============================================================================
__global__ __launch_bounds__(512, 4) void k_conv(const bf16* __restrict__ Xt, const bf16* __restrict__ W,
                                                 const float* __restrict__ bias, bf16* __restrict__ out,
                                                 int outBatchStride, int outRowOff, int applyRelu,
                                                 float* __restrict__ statSum, float* __restrict__ statSq)
{
  __shared__ bf16 sAll[32768];   // 64 KB: A dbuf 2x16KB @0, B dbuf 2x8KB @32KB; C-tile overlay
  const int flat = blockIdx.x + (blockIdx.z << 5);  // [0,512)
  const int xcd = flat & 7, slot = flat >> 3;       // slot in [0,64)
  const int b = 2*xcd + (slot >> 5);
  const int l0 = (slot & 31) * 128;
  const int tid = threadIdx.x, lane = tid & 63, wid = tid >> 6;
  const int wr = wid >> 1, wc = wid & 1;            // 4 M-waves x 2 N-waves
  const int frow = lane & 15, g = lane >> 4;
  f32x4 acc[4][4] = {};

#define CONV_STAGE(kt, bufi) { \
    const int ct3 = (kt)/3, tt = (kt) - ct3*3, c0 = ct3*32; \
    const bf16* Ab = W  + (((size_t)b*3 + tt)*256)*256 + c0; \
    const bf16* Bb = Xt + ((size_t)b*4098 + l0 + tt)*256 + c0; \
    _Pragma("unroll") \
    for (int j = 0; j < 2; ++j){ \
      const int q = tid + j*512, r = q >> 2, s3 = q & 3; \
      const int cc = (s3 ^ ((r >> 1) & 3)) * 8; \
      gload16(Ab + (size_t)r*256 + cc, &sAll[(bufi)*8192 + q*8]); \
    } \
    { const int q = tid, r = q >> 2, s3 = q & 3; \
      const int cc = (s3 ^ ((r >> 1) & 3)) * 8; \
      gload16(Bb + (size_t)r*256 + cc, &sAll[16384 + (bufi)*4096 + q*8]); } \
  }

  CONV_STAGE(0, 0);
  #pragma unroll 1
  for (int kt = 0; kt < 24; ++kt){
    const int buf = kt & 1;
    if (kt + 1 < 24){
      CONV_STAGE(kt+1, buf^1);
      asm volatile("s_waitcnt vmcnt(3)" ::: "memory");   // drain glds(kt) only
    } else {
      asm volatile("s_waitcnt vmcnt(0)" ::: "memory");
    }
    __builtin_amdgcn_s_barrier();
    const bf16* pA = sAll + buf*8192;
    const bf16* pB = sAll + 16384 + buf*4096;
    short8 bfr[4], afr[4];
    #pragma unroll
    for (int n = 0; n < 4; ++n){
      const int row = wc*64 + n*16 + frow;               // l in [0,128)
      const int sl = g ^ ((row >> 1) & 3);
      bfr[n] = *reinterpret_cast<const short8*>(pB + row*32 + sl*8);
    }
    #pragma unroll
    for (int m = 0; m < 4; ++m){
      const int row = wr*64 + m*16 + frow;               // o in [0,256)
      const int sl = g ^ ((row >> 1) & 3);
      afr[m] = *reinterpret_cast<const short8*>(pA + row*32 + sl*8);
    }
    __builtin_amdgcn_s_setprio(1);
    #pragma unroll
    for (int m = 0; m < 4; ++m)
      #pragma unroll
      for (int n = 0; n < 4; ++n)
        acc[m][n] = __builtin_amdgcn_mfma_f32_16x16x32_bf16(afr[m], bfr[n], acc[m][n], 0, 0, 0);
    __builtin_amdgcn_s_setprio(0);
    __builtin_amdgcn_s_barrier();
  }
#undef CONV_STAGE

  // epilogue: bias/relu/stats; acc -> swizzled LDS C-tile [128 l][256 o];
  // full-line 512 B coalesced blast (no partial-line L2 write-allocate).
  float cs[4][4] = {{0.f}}, cq[4][4] = {{0.f}};
  #pragma unroll
  for (int m = 0; m < 4; ++m){
    const int col = wr*64 + m*16 + g*4;                  // output channel o
    float bi[4] = {0.f, 0.f, 0.f, 0.f};
    if (bias){
      const f32x4 bv = *reinterpret_cast<const f32x4*>(bias + b*256 + col);
      bi[0]=bv[0]; bi[1]=bv[1]; bi[2]=bv[2]; bi[3]=bv[3];
    }
    #pragma unroll
    for (int n = 0; n < 4; ++n){
      const int row = wc*64 + n*16 + frow;               // l in [0,128)
      float v[4];
      #pragma unroll
      for (int j = 0; j < 4; ++j){
        v[j] = acc[m][n][j] + bi[j];
        if (applyRelu) v[j] = fmaxf(v[j], 0.f);
        cs[m][j] += v[j];
        cq[m][j] += v[j]*v[j];
      }
      uint2v pk;
      pk[0] = (unsigned)f2b(v[0]) | ((unsigned)f2b(v[1]) << 16);
      pk[1] = (unsigned)f2b(v[2]) | ((unsigned)f2b(v[3]) << 16);
      const int chunk = (col >> 3) ^ (row & 31);
      *reinterpret_cast<uint2v*>((char*)sAll + row*512 + chunk*16 + (g&1)*8) = pk;
    }
  }
  __syncthreads();
  {
    char* gp = (char*)out + 2*((size_t)b*outBatchStride + (size_t)(l0 + outRowOff)*256);
    #pragma unroll
    for (int it = 0; it < 8; ++it){
      const int row = it*16 + (tid >> 5);
      const int c = tid & 31;
      const int cs2 = c ^ (row & 31);
      const uint4v v = *reinterpret_cast<const uint4v*>((const char*)sAll + row*512 + cs2*16);
      *reinterpret_cast<uint4v*>(gp + (size_t)row*512 + c*16) = v;
    }
  }
  if (statSum){
    #pragma unroll
    for (int m = 0; m < 4; ++m)
      #pragma unroll
      for (int j = 0; j < 4; ++j){
        #pragma unroll
        for (int d = 1; d < 16; d <<= 1){
          cs[m][j] += __shfl_xor(cs[m][j], d);
          cq[m][j] += __shfl_xor(cq[m][j], d);
        }
      }
    __syncthreads();                       // blast reads done -> LDS reusable
    float* ls = (float*)sAll;              // [8 waves][64 ch]
    float* lq = ls + 512;
    if (frow == 0){
      #pragma unroll
      for (int m = 0; m < 4; ++m)
        #pragma unroll
        for (int j = 0; j < 4; ++j){
          ls[wid*64 + m*16 + g*4 + j] = cs[m][j];
          lq[wid*64 + m*16 + g*4 + j] = cq[m][j];
        }
    }
    __syncthreads();
    if (tid < 256){
      const int o = tid, wrI = o >> 6, idx = o & 63;
      const float s  = ls[(wrI*2 + 0)*64 + idx] + ls[(wrI*2 + 1)*64 + idx];
      const float qq = lq[(wrI*2 + 0)*64 + idx] + lq[(wrI*2 + 1)*64 + idx];
      atomicAdd(statSum + o, s);
      atomicAdd(statSq  + o, qq);
    }
  }
}

__global__ void k_bnfin(const float* __restrict__ sum, const float* __restrict__ sq,
                        const float* __restrict__ g, const float* __restrict__ bb,
                        float* __restrict__ scale, float* __restrict__ shift)
{
  const int o = threadIdx.x;
  const float inv = 1.f/65536.f;
  const float m = sum[o]*inv;
  const float v = fmaxf(sq[o]*inv - m*m, 0.f);
  const float sc = g[o] / sqrtf(v + 1e-5f);
  scale[o] = sc;
  shift[o] = bb[o] - m*sc;
}

// ---- h2T[b][lp][o] = relu(y2T[b][lp-1][o]*scale+shift), pads zeroed ----
__global__ __launch_bounds__(256) void k_norm2(const bf16* __restrict__ y, const float* __restrict__ scale,
                                               const float* __restrict__ shift, bf16* __restrict__ h)
{
  const int gr = blockIdx.x*8 + (threadIdx.x >> 5);
  const int oc = threadIdx.x & 31;
  const int b = gr / 4098, lp = gr - b*4098;
  unsigned short* dst = (unsigned short*)h + (size_t)gr*256 + oc*8;
  if (lp == 0 || lp == 4097){
    uint4v z = {0u,0u,0u,0u};
    *reinterpret_cast<uint4v*>(dst) = z;
    return;
  }
  const unsigned short* src = (const unsigned short*)y + ((size_t)b*4096 + (lp-1))*256 + oc*8;
  const uint4v in = *reinterpret_cast<const uint4v*>(src);
  const f32x4 sA0 = *reinterpret_cast<const f32x4*>(scale + oc*8);
  const f32x4 sA1 = *reinterpret_cast<const f32x4*>(scale + oc*8 + 4);
  const f32x4 hA0 = *reinterpret_cast<const f32x4*>(shift + oc*8);
  const f32x4 hA1 = *reinterpret_cast<const f32x4*>(shift + oc*8 + 4);
  uint4v ov;
  #pragma unroll
  for (int e = 0; e < 4; ++e){
    const unsigned int w = in[e];
    const float sc0 = (e<2) ? sA0[2*e] : sA1[2*e-4];
    const float sc1 = (e<2) ? sA0[2*e+1] : sA1[2*e-3];
    const float sh0 = (e<2) ? hA0[2*e] : hA1[2*e-4];
    const float sh1 = (e<2) ? hA0[2*e+1] : hA1[2*e-3];
    const float v0 = fmaxf(b2f((unsigned short)(w & 0xffffu))*sc0 + sh0, 0.f);
    const float v1 = fmaxf(b2f((unsigned short)(w >> 16))*sc1 + sh1, 0.f);
    ov[e] = (unsigned)f2b(v0) | ((unsigned)f2b(v1) << 16);
  }
  *reinterpret_cast<uint4v*>(dst) = ov;
}

// ---- h3 = relu(y3*scale+shift) in-place, plus per-(b,o) sums for SE ----
__global__ __launch_bounds__(256) void k_norm3(bf16* __restrict__ y, const float* __restrict__ scale,
                                               const float* __restrict__ shift, float* __restrict__ s_sum)
{
  __shared__ float red[8][256];
  const int tid = threadIdx.x;
  const int rr = tid >> 5, oc = tid & 31;
  const size_t row = (size_t)blockIdx.x*8 + rr;
  const int b = (int)(row >> 12);
  unsigned short* p = (unsigned short*)y + row*256 + oc*8;
  const uint4v in = *reinterpret_cast<const uint4v*>(p);
  const f32x4 sA0 = *reinterpret_cast<const f32x4*>(scale + oc*8);
  const f32x4 sA1 = *reinterpret_cast<const f32x4*>(scale + oc*8 + 4);
  const f32x4 hA0 = *reinterpret_cast<const f32x4*>(shift + oc*8);
  const f32x4 hA1 = *reinterpret_cast<const f32x4*>(shift + oc*8 + 4);
  uint4v ov;
  float loc[8];
  #pragma unroll
  for (int e = 0; e < 4; ++e){
    const unsigned int w = in[e];
    const float sc0 = (e<2) ? sA0[2*e] : sA1[2*e-4];
    const float sc1 = (e<2) ? sA0[2*e+1] : sA1[2*e-3];
    const float sh0 = (e<2) ? hA0[2*e] : hA1[2*e-4];
    const float sh1 = (e<2) ? hA0[2*e+1] : hA1[2*e-3];
    const float v0 = fmaxf(b2f((unsigned short)(w & 0xffffu))*sc0 + sh0, 0.f);
    const float v1 = fmaxf(b2f((unsigned short)(w >> 16))*sc1 + sh1, 0.f);
    loc[2*e] = v0; loc[2*e+1] = v1;
    ov[e] = (unsigned)f2b(v0) | ((unsigned)f2b(v1) << 16);
  }
  *reinterpret_cast<uint4v*>(p) = ov;
  #pragma unroll
  for (int j = 0; j < 8; ++j) red[rr][oc*8 + j] = loc[j];
  __syncthreads();
  const int o = tid;
  float tot = 0.f;
  #pragma unroll
  for (int r2 = 0; r2 < 8; ++r2) tot += red[r2][o];
  atomicAdd(&s_sum[(size_t)b*256 + o], tot);
}

// ---- SE: s2[b][o] = sigmoid(W2 @ relu(W1 @ mean + b1) + b2) ----
__global__ __launch_bounds__(256) void k_se(const float* __restrict__ s_sum, const float* __restrict__ w1,
                                            const float* __restrict__ b1, const float* __restrict__ w2,
                                            const float* __restrict__ b2, float* __restrict__ s2)
{
  __shared__ float sv[256];
  __shared__ float t1[256];
  const int b = blockIdx.x, o = threadIdx.x;
  sv[o] = s_sum[(size_t)b*256 + o] * (1.f/4096.f);
  __syncthreads();
  float a = b1[o];
  for (int c = 0; c < 256; ++c) a += w1[(size_t)o*256 + c] * sv[c];
  t1[o] = fmaxf(a, 0.f);
  __syncthreads();
  float a2 = b2[o];
  for (int c = 0; c < 256; ++c) a2 += w2[(size_t)o*256 + c] * t1[c];
  s2[(size_t)b*256 + o] = 1.f / (1.f + expf(-a2));
}

// ---- out[b][o][l] = relu(h3T[b][l][o]*s2[b][o] + x[b][o][l]) ----
__global__ __launch_bounds__(256) void k_final(const bf16* __restrict__ h3, const float* __restrict__ s2,
                                               const float* __restrict__ x, float* __restrict__ out)
{
  __shared__ float tile[64][65];
  const int b = blockIdx.z, o0 = blockIdx.y*64, l0 = blockIdx.x*64;
  const int tid = threadIdx.x;
  {
    const int r = tid >> 2, q = tid & 3;
    const unsigned short* src = (const unsigned short*)h3 + ((size_t)b*4096 + l0 + r)*256 + o0 + q*16;
    const uint4v a0 = *reinterpret_cast<const uint4v*>(src);
    const uint4v a1 = *reinterpret_cast<const uint4v*>(src + 8);
    #pragma unroll
    for (int e = 0; e < 4; ++e){
      tile[r][q*16 + 2*e]         = b2f((unsigned short)(a0[e] & 0xffffu));
      tile[r][q*16 + 2*e + 1]     = b2f((unsigned short)(a0[e] >> 16));
      tile[r][q*16 + 8 + 2*e]     = b2f((unsigned short)(a1[e] & 0xffffu));
      tile[r][q*16 + 8 + 2*e + 1] = b2f((unsigned short)(a1[e] >> 16));
    }
  }
  __syncthreads();
  {
    const int orow = tid >> 2, q = tid & 3;
    const int o = o0 + orow;
    const float sc = s2[(size_t)b*256 + o];
    const float* xs = x + ((size_t)b*256 + o)*4096 + l0 + q*16;
    float* dst = out + ((size_t)b*256 + o)*4096 + l0 + q*16;
    #pragma unroll
    for (int k = 0; k < 16; k += 4){
      const f32x4 xv = *reinterpret_cast<const f32x4*>(xs + k);
      f32x4 r;
      #pragma unroll
      for (int e = 0; e < 4; ++e)
        r[e] = fmaxf(tile[q*16 + k + e][orow]*sc + xv[e], 0.f);
      *reinterpret_cast<f32x4*>(dst + k) = r;
    }
  }
}

extern "C" void kernel_launch(void* const* d_in, const int* in_sizes, int n_in,
                              void* d_out, int out_size, void* d_ws, size_t ws_size,
                              hipStream_t stream)
{
  const float* x     = (const float*)d_in[0];
  const float* att1  = (const float*)d_in[1];
  const float* att2  = (const float*)d_in[2];
  const float* att3  = (const float*)d_in[3];
  const float* w1_w  = (const float*)d_in[4];
  const float* w1_b  = (const float*)d_in[5];
  const float* w2_w  = (const float*)d_in[6];
  const float* w2_b  = (const float*)d_in[7];
  const float* w3_w  = (const float*)d_in[8];
  const float* w3_b  = (const float*)d_in[9];
  const float* b1_w  = (const float*)d_in[10];
  const float* b1_b  = (const float*)d_in[11];
  const float* bn2_w = (const float*)d_in[12];
  const float* bn2_b = (const float*)d_in[13];
  const float* bn3_w = (const float*)d_in[14];
  const float* bn3_b = (const float*)d_in[15];
  const float* se1_w = (const float*)d_in[16];
  const float* se1_b = (const float*)d_in[17];
  const float* se2_w = (const float*)d_in[18];
  const float* se2_b = (const float*)d_in[19];

  char* ws = (char*)d_ws;
  // workspace layout (bytes)
  bf16*  xT   = (bf16*)(ws + 0);           // [16][4098][256]  (reused as y3T/h3T)
  bf16*  h1T  = (bf16*)(ws + 33570816);    // [16][4098][256]
  bf16*  y2T  = (bf16*)(ws + 67141632);    // [16][4096][256]
  bf16*  h2T  = (bf16*)(ws + 100696064);   // [16][4098][256]
  bf16*  Wt   = (bf16*)(ws + 134266880);   // [3][16][3][256][256]
  bf16*  wb   = (bf16*)(ws + 178307072);   // [3][768][1024]
  float* b1v  = (float*)(ws + 183025664);  // [4096]
  float* st   = (float*)(ws + 183042048);
  float* bn2sum = st;          // 256
  float* bn2sq  = st + 256;
  float* bn3sum = st + 512;
  float* bn3sq  = st + 768;
  float* s_sum  = st + 1024;   // 4096
  float* scale2 = st + 5120;
  float* shift2 = st + 5376;
  float* scale3 = st + 5632;
  float* shift3 = st + 5888;
  float* s2v    = st + 6144;   // 4096
  bf16*  y3T  = (bf16*)(ws + 0);           // overlay on xT (dead after conv1)

  // zero accumulators (bn2/bn3 sums + s_sum = 5120 floats)
  hipMemsetAsync(st, 0, 5120*sizeof(float), stream);

  k_transpose_x<<<dim3(64,4,16),256,0,stream>>>(x, xT);
  k_zero_pads<<<16,256,0,stream>>>(xT, h1T);
  k_cvt3<<<512,256,0,stream>>>(w1_w, w2_w, w3_w, wb, 768*1024);
  k_gen<<<dim3(16,1,9),512,0,stream>>>(att1, att2, att3, wb, w1_b, w2_b, w3_b, Wt);
  k_b1<<<1024,256,0,stream>>>(att1, b1_w, b1_b, b1v);

  k_conv<<<dim3(32,1,16),512,0,stream>>>(xT,  Wt,                           b1v,     h1T, 4098*256, 1, 1, nullptr, nullptr);
  k_conv<<<dim3(32,1,16),512,0,stream>>>(h1T, Wt + (size_t)1*16*3*256*256,  nullptr, y2T, 4096*256, 0, 0, bn2sum, bn2sq);
  k_bnfin<<<1,256,0,stream>>>(bn2sum, bn2sq, bn2_w, bn2_b, scale2, shift2);
  k_norm2<<<8196,256,0,stream>>>(y2T, scale2, shift2, h2T);
  k_conv<<<dim3(32,1,16),512,0,stream>>>(h2T, Wt + (size_t)2*16*3*256*256,  nullptr, y3T, 4096*256, 0, 0, bn3sum, bn3sq);
  k_bnfin<<<1,256,0,stream>>>(bn3sum, bn3sq, bn3_w, bn3_b, scale3, shift3);
  k_norm3<<<8192,256,0,stream>>>(y3T, scale3, shift3, s_sum);
  k_se<<<16,256,0,stream>>>(s_sum, se1_w, se1_b, se2_w, se2_b, s2v);
  k_final<<<dim3(64,4,16),256,0,stream>>>((const bf16*)y3T, s2v, x, (float*)d_out);
}

// Round 8
// 310.843 us; speedup vs baseline: 1.0549x; 1.0515x over previous
//
#include <hip/hip_runtime.h>
#include <hip/hip_bf16.h>

using bf16 = __hip_bfloat16;
typedef __attribute__((ext_vector_type(4))) float f32x4;
typedef __attribute__((ext_vector_type(8))) short short8;
typedef __attribute__((ext_vector_type(2))) unsigned int uint2v;
typedef __attribute__((ext_vector_type(4))) unsigned int uint4v;

#define DEVI static __device__ __forceinline__

DEVI unsigned short f2b(float f){
  unsigned int u = __float_as_uint(f);
  unsigned int r = (u + 0x7fffu + ((u >> 16) & 1u)) >> 16;
  return (unsigned short)r;
}
DEVI float b2f(unsigned short u){
  return __uint_as_float(((unsigned int)u) << 16);
}

DEVI void gload16(const void* g, void* l){
  __builtin_amdgcn_global_load_lds(
      (const __attribute__((address_space(1))) unsigned int*)g,
      (__attribute__((address_space(3))) unsigned int*)l, 16, 0, 0);
}

// ---- x [16][256][4096] f32 -> xT [16][4098][256] bf16 (row lp = l+1) ----
__global__ __launch_bounds__(256) void k_transpose_x(const float* __restrict__ x,
                                                     bf16* __restrict__ xt)
{
  __shared__ float tile[64][65];
  const int b = blockIdx.z, l0 = blockIdx.x*64, c0 = blockIdx.y*64;
  const int tid = threadIdx.x;
  {
    const int r = tid >> 2, q = tid & 3;
    const float* src = x + ((size_t)(b*256 + c0 + r))*4096 + l0 + q*16;
    #pragma unroll
    for (int j = 0; j < 4; ++j){
      const f32x4 v = *reinterpret_cast<const f32x4*>(src + j*4);
      #pragma unroll
      for (int e = 0; e < 4; ++e) tile[r][q*16 + j*4 + e] = v[e];
    }
  }
  __syncthreads();
  {
    const int jr = tid >> 2, cq = tid & 3;
    unsigned int w[8];
    #pragma unroll
    for (int e = 0; e < 8; ++e){
      const float lo = tile[cq*16 + 2*e][jr];
      const float hi = tile[cq*16 + 2*e + 1][jr];
      w[e] = (unsigned int)f2b(lo) | ((unsigned int)f2b(hi) << 16);
    }
    unsigned short* dst = (unsigned short*)xt + ((size_t)b*4098 + l0 + jr + 1)*256 + c0 + cq*16;
    uint4v a0 = {w[0],w[1],w[2],w[3]}, a1 = {w[4],w[5],w[6],w[7]};
    *reinterpret_cast<uint4v*>(dst)     = a0;
    *reinterpret_cast<uint4v*>(dst + 8) = a1;
  }
}

// ---- zero pad rows (lp=0 and lp=4097) of xT and h1T ----
__global__ void k_zero_pads(bf16* __restrict__ xt, bf16* __restrict__ h1t)
{
  const int b = blockIdx.x, tid = threadIdx.x;
  const size_t top = (size_t)b*4098*256 + tid;
  const size_t bot = (size_t)b*4098*256 + (size_t)4097*256 + tid;
  unsigned short* px = (unsigned short*)xt;
  unsigned short* ph = (unsigned short*)h1t;
  px[top] = 0; px[bot] = 0; ph[top] = 0; ph[bot] = 0;
}

// ---- f32 -> bf16 convert for 3 equally-sized tensors packed into dst (wb only) ----
__global__ __launch_bounds__(256) void k_cvt3(const float* __restrict__ s0, const float* __restrict__ s1,
                                              const float* __restrict__ s2, bf16* __restrict__ dst, int n1)
{
  const size_t total = (size_t)3 * (size_t)n1 / 4;
  for (size_t i = (size_t)blockIdx.x*256 + threadIdx.x; i < total; i += (size_t)gridDim.x*256){
    const size_t e = i*4;
    const int which = (int)(e / (size_t)n1);
    const size_t off = e - (size_t)which*(size_t)n1;
    const float* s = which==0 ? s0 : which==1 ? s1 : s2;
    const f32x4 v = *reinterpret_cast<const f32x4*>(s + off);
    uint2v p;
    p[0] = (unsigned)f2b(v[0]) | ((unsigned)f2b(v[1])<<16);
    p[1] = (unsigned)f2b(v[2]) | ((unsigned)f2b(v[3])<<16);
    *reinterpret_cast<uint2v*>((unsigned short*)dst + e) = p;
  }
}

// ============================================================================
// k_gen (R7 rewrite): Wt[i][bb][t][o][c] = sum_h wb_i[c*3+t][h]*att_i[bo][h]+bias.
// Conv-proven skeleton: BOTH operands via global_load_lds + counted vmcnt(4)
// (no register-latency chain). B (att) staged as RAW F32 (16 KB/buf,
// slot^(row&7) both-sides swizzle), converted to bf16 at fragment-read with
// v_cvt_pk_bf16_f32. Tile 256(c) x 128(bo), BK=32, 8 waves (4M x 2N), acc 64
// VGPR, LDS 64 KB -> 2 blocks/CU; grid 288 blocks, XCD-swizzled (3 taps
// sharing one att tile co-XCD).
// ============================================================================
__global__ __launch_bounds__(512, 4) void k_gen(const float* __restrict__ att1f, const float* __restrict__ att2f,
                                                const float* __restrict__ att3f, const bf16* __restrict__ wbp,
                                                const float* __restrict__ bias0, const float* __restrict__ bias1,
                                                const float* __restrict__ bias2, bf16* __restrict__ Wt)
{
  __shared__ bf16 sAll[32768];   // 64 KB: A dbuf 2x16KB(bf16) @0; B dbuf 2x16KB(f32 raw) @32KB
  const int flat = blockIdx.x + (blockIdx.z << 5);  // x [0,32), z [0,9) -> [0,288)
  const int xcd = flat & 7, s = flat >> 3;          // s in [0,36)
  const int t = s % 3, u = s / 3;                   // u in [0,12)
  const int tau = u*8 + xcd;                        // [0,96)
  const int i = tau >> 5, boc = tau & 31;           // i [0,3), boc [0,32)
  const int bo0 = boc*128;
  const bf16*  __restrict__ A  = wbp + (size_t)i*768*1024 + (size_t)t*1024;
  const float* __restrict__ Bf = ((i==0) ? att1f : (i==1) ? att2f : att3f) + (size_t)bo0*1024;
  const float* __restrict__ bias = (i==0) ? bias0 : (i==1) ? bias1 : bias2;
  const int tid = threadIdx.x, lane = tid & 63, wid = tid >> 6;
  const int wr = wid >> 1, wc = wid & 1;            // 4 M-waves (c) x 2 N-waves (bo)
  const int frow = lane & 15, g = lane >> 4;
  f32x4 acc[4][4] = {};

#define GEN_STAGE(kt, bufi) { \
    _Pragma("unroll") \
    for (int j = 0; j < 2; ++j){ \
      const int q = tid + j*512, r = q >> 2, s3 = q & 3; \
      const int cc = (s3 ^ ((r >> 1) & 3)) * 8; \
      gload16(A + (size_t)r*3072 + (kt)*32 + cc, (char*)sAll + (bufi)*16384 + q*16); \
    } \
    _Pragma("unroll") \
    for (int j = 0; j < 2; ++j){ \
      const int q = tid + j*512, r = q >> 3, s7 = q & 7; \
      const int ss = s7 ^ (r & 7); \
      gload16(Bf + (size_t)r*1024 + (kt)*32 + ss*4, (char*)sAll + 32768 + (bufi)*16384 + q*16); \
    } \
  }

  GEN_STAGE(0, 0);
  #pragma unroll 1
  for (int kt = 0; kt < 32; ++kt){
    const int p = kt & 1;
    if (kt + 1 < 32){
      GEN_STAGE(kt+1, p^1);
      asm volatile("s_waitcnt vmcnt(4)" ::: "memory");   // drain tile kt only
    } else {
      asm volatile("s_waitcnt vmcnt(0)" ::: "memory");
    }
    __builtin_amdgcn_s_barrier();
    const char* pA = (const char*)sAll + p*16384;
    const char* pB = (const char*)sAll + 32768 + p*16384;
    short8 bfr[4];
    #pragma unroll
    for (int n = 0; n < 4; ++n){
      const int row = wc*64 + n*16 + frow;               // bo in [0,128)
      const f32x4 f0 = *reinterpret_cast<const f32x4*>(pB + row*128 + (((2*g)  ^ (row & 7))*16));
      const f32x4 f1 = *reinterpret_cast<const f32x4*>(pB + row*128 + (((2*g+1)^ (row & 7))*16));
      unsigned int w0, w1, w2, w3;
      asm("v_cvt_pk_bf16_f32 %0, %1, %2" : "=v"(w0) : "v"(f0[0]), "v"(f0[1]));
      asm("v_cvt_pk_bf16_f32 %0, %1, %2" : "=v"(w1) : "v"(f0[2]), "v"(f0[3]));
      asm("v_cvt_pk_bf16_f32 %0, %1, %2" : "=v"(w2) : "v"(f1[0]), "v"(f1[1]));
      asm("v_cvt_pk_bf16_f32 %0, %1, %2" : "=v"(w3) : "v"(f1[2]), "v"(f1[3]));
      union { uint4v u; short8 sv; } cvtu;
      cvtu.u[0] = w0; cvtu.u[1] = w1; cvtu.u[2] = w2; cvtu.u[3] = w3;
      bfr[n] = cvtu.sv;
    }
    __builtin_amdgcn_s_setprio(1);
    #pragma unroll
    for (int m = 0; m < 4; ++m){
      const int row = wr*64 + m*16 + frow;               // c in [0,256)
      const int sl = g ^ ((row >> 1) & 3);
      const short8 af = *reinterpret_cast<const short8*>(pA + row*64 + sl*16);
      #pragma unroll
      for (int n = 0; n < 4; ++n)
        acc[m][n] = __builtin_amdgcn_mfma_f32_16x16x32_bf16(af, bfr[n], acc[m][n], 0, 0, 0);
    }
    __builtin_amdgcn_s_setprio(0);
    __builtin_amdgcn_s_barrier();
  }
#undef GEN_STAGE

  // epilogue: C-tile [128 bo][256 c] bf16 = 64 KB LDS overlay (staging dead),
  // chunk^(row&31) swizzle, then full-line 512 B coalesced blast.
  #pragma unroll
  for (int m = 0; m < 4; ++m){
    const int col = wr*64 + m*16 + g*4;                  // c
    float bi[4];
    #pragma unroll
    for (int j = 0; j < 4; ++j) bi[j] = bias[(col + j)*3 + t];
    #pragma unroll
    for (int n = 0; n < 4; ++n){
      const int row = wc*64 + n*16 + frow;               // bo-row in [0,128)
      uint2v pk;
      pk[0] = (unsigned)f2b(acc[m][n][0] + bi[0]) | ((unsigned)f2b(acc[m][n][1] + bi[1]) << 16);
      pk[1] = (unsigned)f2b(acc[m][n][2] + bi[2]) | ((unsigned)f2b(acc[m][n][3] + bi[3]) << 16);
      const int chunk = (col >> 3) ^ (row & 31);
      *reinterpret_cast<uint2v*>((char*)sAll + row*512 + chunk*16 + (g&1)*8) = pk;
    }
  }
  __syncthreads();
  {
    const int bb = boc >> 1, o0 = (boc & 1)*128;
    char* gp = (char*)Wt + 2*((((size_t)(i*16 + bb)*3 + t)*256 + o0)*256);
    #pragma unroll
    for (int it = 0; it < 8; ++it){
      const int row = it*16 + (tid >> 5);
      const int c = tid & 31;
      const int cs2 = c ^ (row & 31);
      const uint4v v = *reinterpret_cast<const uint4v*>((const char*)sAll + row*512 + cs2*16);
      *reinterpret_cast<uint4v*>(gp + (size_t)row*512 + c*16) = v;
    }
  }
}

// ---- b1[b*256+o] = att1[bo,:] . b1_w + b1_b ----
__global__ __launch_bounds__(256) void k_b1(const float* __restrict__ att1, const float* __restrict__ b1w,
                                            const float* __restrict__ b1b, float* __restrict__ out)
{
  const int m = blockIdx.x*4 + (threadIdx.x >> 6);
  const int lane = threadIdx.x & 63;
  const float* a = att1 + (size_t)m*1024;
  float s = 0.f;
  for (int k = lane*4; k < 1024; k += 256){
    const f32x4 v = *reinterpret_cast<const f32x4*>(a + k);
    const f32x4 w = *reinterpret_cast<const f32x4*>(b1w + k);
    s += v[0]*w[0] + v[1]*w[1] + v[2]*w[2] + v[3]*w[3];
  }
  #pragma unroll
  for (int d = 32; d > 0; d >>= 1) s += __shfl_down(s, d);
  if (lane == 0) out[m] = s + b1b[0];
}

// ============================================================================
// k_conv: out[b][l][o](+rowOff) = sum_t sum_c W[b][t][o][c] * Xt[b][l+t][c].
// Tile BM=256 (o) x BN=128 (l), BK=32, 24 K-steps (tap-inner); 8 waves =
// 4M x 2N, per-wave 64x64 -> 2 blocks/CU. Counted-vmcnt 2-barrier loop.
// ============================================================================
__global__ __launch_bounds__(512, 4) void k_conv(const bf16* __restrict__ Xt, const bf16* __restrict__ W,
                                                 const float* __restrict__ bias, bf16* __restrict__ out,
                                                 int outBatchStride, int outRowOff, int applyRelu,
                                                 float* __restrict__ statSum, float* __restrict__ statSq)
{
  __shared__ bf16 sAll[32768];   // 64 KB: A dbuf 2x16KB @0, B dbuf 2x8KB @32KB; C-tile overlay
  const int flat = blockIdx.x + (blockIdx.z << 5);  // [0,512)
  const int xcd = flat & 7, slot = flat >> 3;       // slot in [0,64)
  const int b = 2*xcd + (slot >> 5);
  const int l0 = (slot & 31) * 128;
  const int tid = threadIdx.x, lane = tid & 63, wid = tid >> 6;
  const int wr = wid >> 1, wc = wid & 1;            // 4 M-waves x 2 N-waves
  const int frow = lane & 15, g = lane >> 4;
  f32x4 acc[4][4] = {};

#define CONV_STAGE(kt, bufi) { \
    const int ct3 = (kt)/3, tt = (kt) - ct3*3, c0 = ct3*32; \
    const bf16* Ab = W  + (((size_t)b*3 + tt)*256)*256 + c0; \
    const bf16* Bb = Xt + ((size_t)b*4098 + l0 + tt)*256 + c0; \
    _Pragma("unroll") \
    for (int j = 0; j < 2; ++j){ \
      const int q = tid + j*512, r = q >> 2, s3 = q & 3; \
      const int cc = (s3 ^ ((r >> 1) & 3)) * 8; \
      gload16(Ab + (size_t)r*256 + cc, &sAll[(bufi)*8192 + q*8]); \
    } \
    { const int q = tid, r = q >> 2, s3 = q & 3; \
      const int cc = (s3 ^ ((r >> 1) & 3)) * 8; \
      gload16(Bb + (size_t)r*256 + cc, &sAll[16384 + (bufi)*4096 + q*8]); } \
  }

  CONV_STAGE(0, 0);
  #pragma unroll 1
  for (int kt = 0; kt < 24; ++kt){
    const int buf = kt & 1;
    if (kt + 1 < 24){
      CONV_STAGE(kt+1, buf^1);
      asm volatile("s_waitcnt vmcnt(3)" ::: "memory");   // drain glds(kt) only
    } else {
      asm volatile("s_waitcnt vmcnt(0)" ::: "memory");
    }
    __builtin_amdgcn_s_barrier();
    const bf16* pA = sAll + buf*8192;
    const bf16* pB = sAll + 16384 + buf*4096;
    short8 bfr[4], afr[4];
    #pragma unroll
    for (int n = 0; n < 4; ++n){
      const int row = wc*64 + n*16 + frow;               // l in [0,128)
      const int sl = g ^ ((row >> 1) & 3);
      bfr[n] = *reinterpret_cast<const short8*>(pB + row*32 + sl*8);
    }
    #pragma unroll
    for (int m = 0; m < 4; ++m){
      const int row = wr*64 + m*16 + frow;               // o in [0,256)
      const int sl = g ^ ((row >> 1) & 3);
      afr[m] = *reinterpret_cast<const short8*>(pA + row*32 + sl*8);
    }
    __builtin_amdgcn_s_setprio(1);
    #pragma unroll
    for (int m = 0; m < 4; ++m)
      #pragma unroll
      for (int n = 0; n < 4; ++n)
        acc[m][n] = __builtin_amdgcn_mfma_f32_16x16x32_bf16(afr[m], bfr[n], acc[m][n], 0, 0, 0);
    __builtin_amdgcn_s_setprio(0);
    __builtin_amdgcn_s_barrier();
  }
#undef CONV_STAGE

  // epilogue: bias/relu/stats; acc -> swizzled LDS C-tile [128 l][256 o];
  // full-line 512 B coalesced blast (no partial-line L2 write-allocate).
  float cs[4][4] = {{0.f}}, cq[4][4] = {{0.f}};
  #pragma unroll
  for (int m = 0; m < 4; ++m){
    const int col = wr*64 + m*16 + g*4;                  // output channel o
    float bi[4] = {0.f, 0.f, 0.f, 0.f};
    if (bias){
      const f32x4 bv = *reinterpret_cast<const f32x4*>(bias + b*256 + col);
      bi[0]=bv[0]; bi[1]=bv[1]; bi[2]=bv[2]; bi[3]=bv[3];
    }
    #pragma unroll
    for (int n = 0; n < 4; ++n){
      const int row = wc*64 + n*16 + frow;               // l in [0,128)
      float v[4];
      #pragma unroll
      for (int j = 0; j < 4; ++j){
        v[j] = acc[m][n][j] + bi[j];
        if (applyRelu) v[j] = fmaxf(v[j], 0.f);
        cs[m][j] += v[j];
        cq[m][j] += v[j]*v[j];
      }
      uint2v pk;
      pk[0] = (unsigned)f2b(v[0]) | ((unsigned)f2b(v[1]) << 16);
      pk[1] = (unsigned)f2b(v[2]) | ((unsigned)f2b(v[3]) << 16);
      const int chunk = (col >> 3) ^ (row & 31);
      *reinterpret_cast<uint2v*>((char*)sAll + row*512 + chunk*16 + (g&1)*8) = pk;
    }
  }
  __syncthreads();
  {
    char* gp = (char*)out + 2*((size_t)b*outBatchStride + (size_t)(l0 + outRowOff)*256);
    #pragma unroll
    for (int it = 0; it < 8; ++it){
      const int row = it*16 + (tid >> 5);
      const int c = tid & 31;
      const int cs2 = c ^ (row & 31);
      const uint4v v = *reinterpret_cast<const uint4v*>((const char*)sAll + row*512 + cs2*16);
      *reinterpret_cast<uint4v*>(gp + (size_t)row*512 + c*16) = v;
    }
  }
  if (statSum){
    #pragma unroll
    for (int m = 0; m < 4; ++m)
      #pragma unroll
      for (int j = 0; j < 4; ++j){
        #pragma unroll
        for (int d = 1; d < 16; d <<= 1){
          cs[m][j] += __shfl_xor(cs[m][j], d);
          cq[m][j] += __shfl_xor(cq[m][j], d);
        }
      }
    __syncthreads();                       // blast reads done -> LDS reusable
    float* ls = (float*)sAll;              // [8 waves][64 ch]
    float* lq = ls + 512;
    if (frow == 0){
      #pragma unroll
      for (int m = 0; m < 4; ++m)
        #pragma unroll
        for (int j = 0; j < 4; ++j){
          ls[wid*64 + m*16 + g*4 + j] = cs[m][j];
          lq[wid*64 + m*16 + g*4 + j] = cq[m][j];
        }
    }
    __syncthreads();
    if (tid < 256){
      const int o = tid, wrI = o >> 6, idx = o & 63;
      const float s  = ls[(wrI*2 + 0)*64 + idx] + ls[(wrI*2 + 1)*64 + idx];
      const float qq = lq[(wrI*2 + 0)*64 + idx] + lq[(wrI*2 + 1)*64 + idx];
      atomicAdd(statSum + o, s);
      atomicAdd(statSq  + o, qq);
    }
  }
}

__global__ void k_bnfin(const float* __restrict__ sum, const float* __restrict__ sq,
                        const float* __restrict__ g, const float* __restrict__ bb,
                        float* __restrict__ scale, float* __restrict__ shift)
{
  const int o = threadIdx.x;
  const float inv = 1.f/65536.f;
  const float m = sum[o]*inv;
  const float v = fmaxf(sq[o]*inv - m*m, 0.f);
  const float sc = g[o] / sqrtf(v + 1e-5f);
  scale[o] = sc;
  shift[o] = bb[o] - m*sc;
}

// ---- h2T[b][lp][o] = relu(y2T[b][lp-1][o]*scale+shift), pads zeroed ----
__global__ __launch_bounds__(256) void k_norm2(const bf16* __restrict__ y, const float* __restrict__ scale,
                                               const float* __restrict__ shift, bf16* __restrict__ h)
{
  const int gr = blockIdx.x*8 + (threadIdx.x >> 5);
  const int oc = threadIdx.x & 31;
  const int b = gr / 4098, lp = gr - b*4098;
  unsigned short* dst = (unsigned short*)h + (size_t)gr*256 + oc*8;
  if (lp == 0 || lp == 4097){
    uint4v z = {0u,0u,0u,0u};
    *reinterpret_cast<uint4v*>(dst) = z;
    return;
  }
  const unsigned short* src = (const unsigned short*)y + ((size_t)b*4096 + (lp-1))*256 + oc*8;
  const uint4v in = *reinterpret_cast<const uint4v*>(src);
  const f32x4 sA0 = *reinterpret_cast<const f32x4*>(scale + oc*8);
  const f32x4 sA1 = *reinterpret_cast<const f32x4*>(scale + oc*8 + 4);
  const f32x4 hA0 = *reinterpret_cast<const f32x4*>(shift + oc*8);
  const f32x4 hA1 = *reinterpret_cast<const f32x4*>(shift + oc*8 + 4);
  uint4v ov;
  #pragma unroll
  for (int e = 0; e < 4; ++e){
    const unsigned int w = in[e];
    const float sc0 = (e<2) ? sA0[2*e] : sA1[2*e-4];
    const float sc1 = (e<2) ? sA0[2*e+1] : sA1[2*e-3];
    const float sh0 = (e<2) ? hA0[2*e] : hA1[2*e-4];
    const float sh1 = (e<2) ? hA0[2*e+1] : hA1[2*e-3];
    const float v0 = fmaxf(b2f((unsigned short)(w & 0xffffu))*sc0 + sh0, 0.f);
    const float v1 = fmaxf(b2f((unsigned short)(w >> 16))*sc1 + sh1, 0.f);
    ov[e] = (unsigned)f2b(v0) | ((unsigned)f2b(v1) << 16);
  }
  *reinterpret_cast<uint4v*>(dst) = ov;
}

// ---- h3 = relu(y3*scale+shift) in-place, plus per-(b,o) sums for SE ----
__global__ __launch_bounds__(256) void k_norm3(bf16* __restrict__ y, const float* __restrict__ scale,
                                               const float* __restrict__ shift, float* __restrict__ s_sum)
{
  __shared__ float red[8][256];
  const int tid = threadIdx.x;
  const int rr = tid >> 5, oc = tid & 31;
  const size_t row = (size_t)blockIdx.x*8 + rr;
  const int b = (int)(row >> 12);
  unsigned short* p = (unsigned short*)y + row*256 + oc*8;
  const uint4v in = *reinterpret_cast<const uint4v*>(p);
  const f32x4 sA0 = *reinterpret_cast<const f32x4*>(scale + oc*8);
  const f32x4 sA1 = *reinterpret_cast<const f32x4*>(scale + oc*8 + 4);
  const f32x4 hA0 = *reinterpret_cast<const f32x4*>(shift + oc*8);
  const f32x4 hA1 = *reinterpret_cast<const f32x4*>(shift + oc*8 + 4);
  uint4v ov;
  float loc[8];
  #pragma unroll
  for (int e = 0; e < 4; ++e){
    const unsigned int w = in[e];
    const float sc0 = (e<2) ? sA0[2*e] : sA1[2*e-4];
    const float sc1 = (e<2) ? sA0[2*e+1] : sA1[2*e-3];
    const float sh0 = (e<2) ? hA0[2*e] : hA1[2*e-4];
    const float sh1 = (e<2) ? hA0[2*e+1] : hA1[2*e-3];
    const float v0 = fmaxf(b2f((unsigned short)(w & 0xffffu))*sc0 + sh0, 0.f);
    const float v1 = fmaxf(b2f((unsigned short)(w >> 16))*sc1 + sh1, 0.f);
    loc[2*e] = v0; loc[2*e+1] = v1;
    ov[e] = (unsigned)f2b(v0) | ((unsigned)f2b(v1) << 16);
  }
  *reinterpret_cast<uint4v*>(p) = ov;
  #pragma unroll
  for (int j = 0; j < 8; ++j) red[rr][oc*8 + j] = loc[j];
  __syncthreads();
  const int o = tid;
  float tot = 0.f;
  #pragma unroll
  for (int r2 = 0; r2 < 8; ++r2) tot += red[r2][o];
  atomicAdd(&s_sum[(size_t)b*256 + o], tot);
}

// ---- SE: s2[b][o] = sigmoid(W2 @ relu(W1 @ mean + b1) + b2) ----
__global__ __launch_bounds__(256) void k_se(const float* __restrict__ s_sum, const float* __restrict__ w1,
                                            const float* __restrict__ b1, const float* __restrict__ w2,
                                            const float* __restrict__ b2, float* __restrict__ s2)
{
  __shared__ float sv[256];
  __shared__ float t1[256];
  const int b = blockIdx.x, o = threadIdx.x;
  sv[o] = s_sum[(size_t)b*256 + o] * (1.f/4096.f);
  __syncthreads();
  float a = b1[o];
  for (int c = 0; c < 256; ++c) a += w1[(size_t)o*256 + c] * sv[c];
  t1[o] = fmaxf(a, 0.f);
  __syncthreads();
  float a2 = b2[o];
  for (int c = 0; c < 256; ++c) a2 += w2[(size_t)o*256 + c] * t1[c];
  s2[(size_t)b*256 + o] = 1.f / (1.f + expf(-a2));
}

// ---- out[b][o][l] = relu(h3T[b][l][o]*s2[b][o] + x[b][o][l]) ----
__global__ __launch_bounds__(256) void k_final(const bf16* __restrict__ h3, const float* __restrict__ s2,
                                               const float* __restrict__ x, float* __restrict__ out)
{
  __shared__ float tile[64][65];
  const int b = blockIdx.z, o0 = blockIdx.y*64, l0 = blockIdx.x*64;
  const int tid = threadIdx.x;
  {
    const int r = tid >> 2, q = tid & 3;
    const unsigned short* src = (const unsigned short*)h3 + ((size_t)b*4096 + l0 + r)*256 + o0 + q*16;
    const uint4v a0 = *reinterpret_cast<const uint4v*>(src);
    const uint4v a1 = *reinterpret_cast<const uint4v*>(src + 8);
    #pragma unroll
    for (int e = 0; e < 4; ++e){
      tile[r][q*16 + 2*e]         = b2f((unsigned short)(a0[e] & 0xffffu));
      tile[r][q*16 + 2*e + 1]     = b2f((unsigned short)(a0[e] >> 16));
      tile[r][q*16 + 8 + 2*e]     = b2f((unsigned short)(a1[e] & 0xffffu));
      tile[r][q*16 + 8 + 2*e + 1] = b2f((unsigned short)(a1[e] >> 16));
    }
  }
  __syncthreads();
  {
    const int orow = tid >> 2, q = tid & 3;
    const int o = o0 + orow;
    const float sc = s2[(size_t)b*256 + o];
    const float* xs = x + ((size_t)b*256 + o)*4096 + l0 + q*16;
    float* dst = out + ((size_t)b*256 + o)*4096 + l0 + q*16;
    #pragma unroll
    for (int k = 0; k < 16; k += 4){
      const f32x4 xv = *reinterpret_cast<const f32x4*>(xs + k);
      f32x4 r;
      #pragma unroll
      for (int e = 0; e < 4; ++e)
        r[e] = fmaxf(tile[q*16 + k + e][orow]*sc + xv[e], 0.f);
      *reinterpret_cast<f32x4*>(dst + k) = r;
    }
  }
}

extern "C" void kernel_launch(void* const* d_in, const int* in_sizes, int n_in,
                              void* d_out, int out_size, void* d_ws, size_t ws_size,
                              hipStream_t stream)
{
  const float* x     = (const float*)d_in[0];
  const float* att1  = (const float*)d_in[1];
  const float* att2  = (const float*)d_in[2];
  const float* att3  = (const float*)d_in[3];
  const float* w1_w  = (const float*)d_in[4];
  const float* w1_b  = (const float*)d_in[5];
  const float* w2_w  = (const float*)d_in[6];
  const float* w2_b  = (const float*)d_in[7];
  const float* w3_w  = (const float*)d_in[8];
  const float* w3_b  = (const float*)d_in[9];
  const float* b1_w  = (const float*)d_in[10];
  const float* b1_b  = (const float*)d_in[11];
  const float* bn2_w = (const float*)d_in[12];
  const float* bn2_b = (const float*)d_in[13];
  const float* bn3_w = (const float*)d_in[14];
  const float* bn3_b = (const float*)d_in[15];
  const float* se1_w = (const float*)d_in[16];
  const float* se1_b = (const float*)d_in[17];
  const float* se2_w = (const float*)d_in[18];
  const float* se2_b = (const float*)d_in[19];

  char* ws = (char*)d_ws;
  // workspace layout (bytes)
  bf16*  xT   = (bf16*)(ws + 0);           // [16][4098][256]  (reused as y3T/h3T)
  bf16*  h1T  = (bf16*)(ws + 33570816);    // [16][4098][256]
  bf16*  y2T  = (bf16*)(ws + 67141632);    // [16][4096][256]
  bf16*  h2T  = (bf16*)(ws + 100696064);   // [16][4098][256]
  bf16*  Wt   = (bf16*)(ws + 134266880);   // [3][16][3][256][256]
  bf16*  wb   = (bf16*)(ws + 178307072);   // [3][768][1024]
  float* b1v  = (float*)(ws + 183025664);  // [4096]
  float* st   = (float*)(ws + 183042048);
  float* bn2sum = st;          // 256
  float* bn2sq  = st + 256;
  float* bn3sum = st + 512;
  float* bn3sq  = st + 768;
  float* s_sum  = st + 1024;   // 4096
  float* scale2 = st + 5120;
  float* shift2 = st + 5376;
  float* scale3 = st + 5632;
  float* shift3 = st + 5888;
  float* s2v    = st + 6144;   // 4096
  bf16*  y3T  = (bf16*)(ws + 0);           // overlay on xT (dead after conv1)

  // zero accumulators (bn2/bn3 sums + s_sum = 5120 floats)
  hipMemsetAsync(st, 0, 5120*sizeof(float), stream);

  k_transpose_x<<<dim3(64,4,16),256,0,stream>>>(x, xT);
  k_zero_pads<<<16,256,0,stream>>>(xT, h1T);
  k_cvt3<<<512,256,0,stream>>>(w1_w, w2_w, w3_w, wb, 768*1024);
  k_gen<<<dim3(32,1,9),512,0,stream>>>(att1, att2, att3, wb, w1_b, w2_b, w3_b, Wt);
  k_b1<<<1024,256,0,stream>>>(att1, b1_w, b1_b, b1v);

  k_conv<<<dim3(32,1,16),512,0,stream>>>(xT,  Wt,                           b1v,     h1T, 4098*256, 1, 1, nullptr, nullptr);
  k_conv<<<dim3(32,1,16),512,0,stream>>>(h1T, Wt + (size_t)1*16*3*256*256,  nullptr, y2T, 4096*256, 0, 0, bn2sum, bn2sq);
  k_bnfin<<<1,256,0,stream>>>(bn2sum, bn2sq, bn2_w, bn2_b, scale2, shift2);
  k_norm2<<<8196,256,0,stream>>>(y2T, scale2, shift2, h2T);
  k_conv<<<dim3(32,1,16),512,0,stream>>>(h2T, Wt + (size_t)2*16*3*256*256,  nullptr, y3T, 4096*256, 0, 0, bn3sum, bn3sq);
  k_bnfin<<<1,256,0,stream>>>(bn3sum, bn3sq, bn3_w, bn3_b, scale3, shift3);
  k_norm3<<<8192,256,0,stream>>>(y3T, scale3, shift3, s_sum);
  k_se<<<16,256,0,stream>>>(s_sum, se1_w, se1_b, se2_w, se2_b, s2v);
  k_final<<<dim3(64,4,16),256,0,stream>>>((const bf16*)y3T, s2v, x, (float*)d_out);
}

// Round 9
// 309.220 us; speedup vs baseline: 1.0604x; 1.0052x over previous
//
#include <hip/hip_runtime.h>
#include <hip/hip_bf16.h>

using bf16 = __hip_bfloat16;
typedef __attribute__((ext_vector_type(4))) float f32x4;
typedef __attribute__((ext_vector_type(8))) short short8;
typedef __attribute__((ext_vector_type(2))) unsigned int uint2v;
typedef __attribute__((ext_vector_type(4))) unsigned int uint4v;

#define DEVI static __device__ __forceinline__

DEVI unsigned short f2b(float f){
  unsigned int u = __float_as_uint(f);
  unsigned int r = (u + 0x7fffu + ((u >> 16) & 1u)) >> 16;
  return (unsigned short)r;
}
DEVI float b2f(unsigned short u){
  return __uint_as_float(((unsigned int)u) << 16);
}

DEVI void gload16(const void* g, void* l){
  __builtin_amdgcn_global_load_lds(
      (const __attribute__((address_space(1))) unsigned int*)g,
      (__attribute__((address_space(3))) unsigned int*)l, 16, 0, 0);
}

// ---- x [16][256][4096] f32 -> xT [16][4098][256] bf16 (row lp = l+1) ----
__global__ __launch_bounds__(256) void k_transpose_x(const float* __restrict__ x,
                                                     bf16* __restrict__ xt)
{
  __shared__ float tile[64][65];
  const int b = blockIdx.z, l0 = blockIdx.x*64, c0 = blockIdx.y*64;
  const int tid = threadIdx.x;
  {
    const int r = tid >> 2, q = tid & 3;
    const float* src = x + ((size_t)(b*256 + c0 + r))*4096 + l0 + q*16;
    #pragma unroll
    for (int j = 0; j < 4; ++j){
      const f32x4 v = *reinterpret_cast<const f32x4*>(src + j*4);
      #pragma unroll
      for (int e = 0; e < 4; ++e) tile[r][q*16 + j*4 + e] = v[e];
    }
  }
  __syncthreads();
  {
    const int jr = tid >> 2, cq = tid & 3;
    unsigned int w[8];
    #pragma unroll
    for (int e = 0; e < 8; ++e){
      const float lo = tile[cq*16 + 2*e][jr];
      const float hi = tile[cq*16 + 2*e + 1][jr];
      w[e] = (unsigned int)f2b(lo) | ((unsigned int)f2b(hi) << 16);
    }
    unsigned short* dst = (unsigned short*)xt + ((size_t)b*4098 + l0 + jr + 1)*256 + c0 + cq*16;
    uint4v a0 = {w[0],w[1],w[2],w[3]}, a1 = {w[4],w[5],w[6],w[7]};
    *reinterpret_cast<uint4v*>(dst)     = a0;
    *reinterpret_cast<uint4v*>(dst + 8) = a1;
  }
}

// ---- zero pad rows (lp=0 and lp=4097) of xT and h1T ----
__global__ void k_zero_pads(bf16* __restrict__ xt, bf16* __restrict__ h1t)
{
  const int b = blockIdx.x, tid = threadIdx.x;
  const size_t top = (size_t)b*4098*256 + tid;
  const size_t bot = (size_t)b*4098*256 + (size_t)4097*256 + tid;
  unsigned short* px = (unsigned short*)xt;
  unsigned short* ph = (unsigned short*)h1t;
  px[top] = 0; px[bot] = 0; ph[top] = 0; ph[bot] = 0;
}

// ---- f32 -> bf16 convert for 3 equally-sized tensors packed into dst (wb only) ----
__global__ __launch_bounds__(256) void k_cvt3(const float* __restrict__ s0, const float* __restrict__ s1,
                                              const float* __restrict__ s2, bf16* __restrict__ dst, int n1)
{
  const size_t total = (size_t)3 * (size_t)n1 / 4;
  for (size_t i = (size_t)blockIdx.x*256 + threadIdx.x; i < total; i += (size_t)gridDim.x*256){
    const size_t e = i*4;
    const int which = (int)(e / (size_t)n1);
    const size_t off = e - (size_t)which*(size_t)n1;
    const float* s = which==0 ? s0 : which==1 ? s1 : s2;
    const f32x4 v = *reinterpret_cast<const f32x4*>(s + off);
    uint2v p;
    p[0] = (unsigned)f2b(v[0]) | ((unsigned)f2b(v[1])<<16);
    p[1] = (unsigned)f2b(v[2]) | ((unsigned)f2b(v[3])<<16);
    *reinterpret_cast<uint2v*>((unsigned short*)dst + e) = p;
  }
}

// ============================================================================
// k_gen (R8: TLP fix): Wt[i][bb][t][o][c] = sum_h wb_i[c*3+t][h]*att_i[bo][h]+b.
// Same conv-proven counted-vmcnt skeleton, re-tiled 128c x 128bo, 256 threads
// (4 waves 2x2, 64x64/wave), LDS 48 KB -> 3 blocks/CU, grid 576 (2.25/CU avg)
// so cross-block TLP hides the per-iteration att-stream stall (the 1-block/CU
// exposure was R7's 2x loss). B (att) staged raw f32, cvt at fragment read.
// ============================================================================
__global__ __launch_bounds__(256, 3) void k_gen(const float* __restrict__ att1f, const float* __restrict__ att2f,
                                                const float* __restrict__ att3f, const bf16* __restrict__ wbp,
                                                const float* __restrict__ bias0, const float* __restrict__ bias1,
                                                const float* __restrict__ bias2, bf16* __restrict__ Wt)
{
  __shared__ bf16 sAll[24576];   // 48 KB: A dbuf 2x8KB @0; B dbuf 2x16KB @16KB; C 32KB overlay @0
  const int flat = blockIdx.x + blockIdx.z*64;      // [0,576)
  const int xcd = flat & 7, s = flat >> 3;          // s in [0,72)
  const int t = s % 3, u = s / 3;                   // u in [0,24)
  const int ch = u & 1;                             // c-half
  const int tau = (u >> 1)*8 + xcd;                 // [0,96)
  const int i = tau >> 5, boc = tau & 31;           // i [0,3), boc [0,32)
  const int bo0 = boc*128, c0 = ch*128;
  const bf16*  __restrict__ A  = wbp + (size_t)i*768*1024 + (size_t)(c0*3 + t)*1024;
  const float* __restrict__ Bf = ((i==0) ? att1f : (i==1) ? att2f : att3f) + (size_t)bo0*1024;
  const float* __restrict__ bias = (i==0) ? bias0 : (i==1) ? bias1 : bias2;
  const int tid = threadIdx.x, lane = tid & 63, wid = tid >> 6;
  const int wr = wid >> 1, wc = wid & 1;            // 2 M-waves (c) x 2 N-waves (bo)
  const int frow = lane & 15, g = lane >> 4;
  f32x4 acc[4][4] = {};

#define GEN_STAGE(kt, bufi) { \
    _Pragma("unroll") \
    for (int j = 0; j < 2; ++j){ \
      const int q = tid + j*256, r = q >> 2, s3 = q & 3; \
      const int cc = (s3 ^ ((r >> 1) & 3)) * 8; \
      gload16(A + (size_t)r*3072 + (kt)*32 + cc, (char*)sAll + (bufi)*8192 + q*16); \
    } \
    _Pragma("unroll") \
    for (int j = 0; j < 4; ++j){ \
      const int q = tid + j*256, r = q >> 3, s7 = q & 7; \
      const int ss = s7 ^ (r & 7); \
      gload16(Bf + (size_t)r*1024 + (kt)*32 + ss*4, (char*)sAll + 16384 + (bufi)*16384 + q*16); \
    } \
  }

  GEN_STAGE(0, 0);
  #pragma unroll 1
  for (int kt = 0; kt < 32; ++kt){
    const int p = kt & 1;
    if (kt + 1 < 32){
      GEN_STAGE(kt+1, p^1);
      asm volatile("s_waitcnt vmcnt(6)" ::: "memory");   // drain tile kt only
    } else {
      asm volatile("s_waitcnt vmcnt(0)" ::: "memory");
    }
    __builtin_amdgcn_s_barrier();
    const char* pA = (const char*)sAll + p*8192;
    const char* pB = (const char*)sAll + 16384 + p*16384;
    short8 bfr[4];
    #pragma unroll
    for (int n = 0; n < 4; ++n){
      const int row = wc*64 + n*16 + frow;               // bo in [0,128)
      const f32x4 f0 = *reinterpret_cast<const f32x4*>(pB + row*128 + (((2*g)  ^ (row & 7))*16));
      const f32x4 f1 = *reinterpret_cast<const f32x4*>(pB + row*128 + (((2*g+1)^ (row & 7))*16));
      unsigned int w0, w1, w2, w3;
      asm("v_cvt_pk_bf16_f32 %0, %1, %2" : "=v"(w0) : "v"(f0[0]), "v"(f0[1]));
      asm("v_cvt_pk_bf16_f32 %0, %1, %2" : "=v"(w1) : "v"(f0[2]), "v"(f0[3]));
      asm("v_cvt_pk_bf16_f32 %0, %1, %2" : "=v"(w2) : "v"(f1[0]), "v"(f1[1]));
      asm("v_cvt_pk_bf16_f32 %0, %1, %2" : "=v"(w3) : "v"(f1[2]), "v"(f1[3]));
      union { uint4v u; short8 sv; } cvtu;
      cvtu.u[0] = w0; cvtu.u[1] = w1; cvtu.u[2] = w2; cvtu.u[3] = w3;
      bfr[n] = cvtu.sv;
    }
    __builtin_amdgcn_s_setprio(1);
    #pragma unroll
    for (int m = 0; m < 4; ++m){
      const int row = wr*64 + m*16 + frow;               // c-local in [0,128)
      const int sl = g ^ ((row >> 1) & 3);
      const short8 af = *reinterpret_cast<const short8*>(pA + row*64 + sl*16);
      #pragma unroll
      for (int n = 0; n < 4; ++n)
        acc[m][n] = __builtin_amdgcn_mfma_f32_16x16x32_bf16(af, bfr[n], acc[m][n], 0, 0, 0);
    }
    __builtin_amdgcn_s_setprio(0);
    __builtin_amdgcn_s_barrier();
  }
#undef GEN_STAGE

  // epilogue: C-tile [128 bo][128 c] bf16 = 32 KB overlay; chunk^(row&15)
  // swizzle; 256 B/row segments = 2 full aligned 128 B lines (no WA fill).
  #pragma unroll
  for (int m = 0; m < 4; ++m){
    const int lcol = wr*64 + m*16 + g*4;                 // c-local
    float bi[4];
    #pragma unroll
    for (int j = 0; j < 4; ++j) bi[j] = bias[(c0 + lcol + j)*3 + t];
    #pragma unroll
    for (int n = 0; n < 4; ++n){
      const int row = wc*64 + n*16 + frow;               // bo-local in [0,128)
      uint2v pk;
      pk[0] = (unsigned)f2b(acc[m][n][0] + bi[0]) | ((unsigned)f2b(acc[m][n][1] + bi[1]) << 16);
      pk[1] = (unsigned)f2b(acc[m][n][2] + bi[2]) | ((unsigned)f2b(acc[m][n][3] + bi[3]) << 16);
      const int chunk = (lcol >> 3) ^ (row & 15);
      *reinterpret_cast<uint2v*>((char*)sAll + row*256 + chunk*16 + (g&1)*8) = pk;
    }
  }
  __syncthreads();
  {
    const int bb = boc >> 1, o0 = (boc & 1)*128;
    char* gp = (char*)Wt + 2*(((((size_t)(i*16 + bb)*3 + t)*256 + o0)*256) + c0);
    #pragma unroll
    for (int it = 0; it < 8; ++it){
      const int row = it*16 + (tid >> 4);                // o-local
      const int c = tid & 15;
      const int cs2 = c ^ (row & 15);
      const uint4v v = *reinterpret_cast<const uint4v*>((const char*)sAll + row*256 + cs2*16);
      *reinterpret_cast<uint4v*>(gp + (size_t)row*512 + c*16) = v;
    }
  }
}

// ---- b1[b*256+o] = att1[bo,:] . b1_w + b1_b ----
__global__ __launch_bounds__(256) void k_b1(const float* __restrict__ att1, const float* __restrict__ b1w,
                                            const float* __restrict__ b1b, float* __restrict__ out)
{
  const int m = blockIdx.x*4 + (threadIdx.x >> 6);
  const int lane = threadIdx.x & 63;
  const float* a = att1 + (size_t)m*1024;
  float s = 0.f;
  for (int k = lane*4; k < 1024; k += 256){
    const f32x4 v = *reinterpret_cast<const f32x4*>(a + k);
    const f32x4 w = *reinterpret_cast<const f32x4*>(b1w + k);
    s += v[0]*w[0] + v[1]*w[1] + v[2]*w[2] + v[3]*w[3];
  }
  #pragma unroll
  for (int d = 32; d > 0; d >>= 1) s += __shfl_down(s, d);
  if (lane == 0) out[m] = s + b1b[0];
}

// ============================================================================
// k_conv: out[b][l][o](+rowOff) = sum_t sum_c W[b][t][o][c] * Xt[b][l+t][c].
// Tile BM=256 (o) x BN=128 (l), BK=32, 24 K-steps (tap-inner); 8 waves =
// 4M x 2N, per-wave 64x64 -> 2 blocks/CU. Counted-vmcnt 2-barrier loop.
// ============================================================================
__global__ __launch_bounds__(512, 4) void k_conv(const bf16* __restrict__ Xt, const bf16* __restrict__ W,
                                                 const float* __restrict__ bias, bf16* __restrict__ out,
                                                 int outBatchStride, int outRowOff, int applyRelu,
                                                 float* __restrict__ statSum, float* __restrict__ statSq)
{
  __shared__ bf16 sAll[32768];   // 64 KB: A dbuf 2x16KB @0, B dbuf 2x8KB @32KB; C-tile overlay
  const int flat = blockIdx.x + (blockIdx.z << 5);  // [0,512)
  const int xcd = flat & 7, slot = flat >> 3;       // slot in [0,64)
  const int b = 2*xcd + (slot >> 5);
  const int l0 = (slot & 31) * 128;
  const int tid = threadIdx.x, lane = tid & 63, wid = tid >> 6;
  const int wr = wid >> 1, wc = wid & 1;            // 4 M-waves x 2 N-waves
  const int frow = lane & 15, g = lane >> 4;
  f32x4 acc[4][4] = {};

#define CONV_STAGE(kt, bufi) { \
    const int ct3 = (kt)/3, tt = (kt) - ct3*3, c0 = ct3*32; \
    const bf16* Ab = W  + (((size_t)b*3 + tt)*256)*256 + c0; \
    const bf16* Bb = Xt + ((size_t)b*4098 + l0 + tt)*256 + c0; \
    _Pragma("unroll") \
    for (int j = 0; j < 2; ++j){ \
      const int q = tid + j*512, r = q >> 2, s3 = q & 3; \
      const int cc = (s3 ^ ((r >> 1) & 3)) * 8; \
      gload16(Ab + (size_t)r*256 + cc, &sAll[(bufi)*8192 + q*8]); \
    } \
    { const int q = tid, r = q >> 2, s3 = q & 3; \
      const int cc = (s3 ^ ((r >> 1) & 3)) * 8; \
      gload16(Bb + (size_t)r*256 + cc, &sAll[16384 + (bufi)*4096 + q*8]); } \
  }

  CONV_STAGE(0, 0);
  #pragma unroll 1
  for (int kt = 0; kt < 24; ++kt){
    const int buf = kt & 1;
    if (kt + 1 < 24){
      CONV_STAGE(kt+1, buf^1);
      asm volatile("s_waitcnt vmcnt(3)" ::: "memory");   // drain glds(kt) only
    } else {
      asm volatile("s_waitcnt vmcnt(0)" ::: "memory");
    }
    __builtin_amdgcn_s_barrier();
    const bf16* pA = sAll + buf*8192;
    const bf16* pB = sAll + 16384 + buf*4096;
    short8 bfr[4], afr[4];
    #pragma unroll
    for (int n = 0; n < 4; ++n){
      const int row = wc*64 + n*16 + frow;               // l in [0,128)
      const int sl = g ^ ((row >> 1) & 3);
      bfr[n] = *reinterpret_cast<const short8*>(pB + row*32 + sl*8);
    }
    #pragma unroll
    for (int m = 0; m < 4; ++m){
      const int row = wr*64 + m*16 + frow;               // o in [0,256)
      const int sl = g ^ ((row >> 1) & 3);
      afr[m] = *reinterpret_cast<const short8*>(pA + row*32 + sl*8);
    }
    __builtin_amdgcn_s_setprio(1);
    #pragma unroll
    for (int m = 0; m < 4; ++m)
      #pragma unroll
      for (int n = 0; n < 4; ++n)
        acc[m][n] = __builtin_amdgcn_mfma_f32_16x16x32_bf16(afr[m], bfr[n], acc[m][n], 0, 0, 0);
    __builtin_amdgcn_s_setprio(0);
    __builtin_amdgcn_s_barrier();
  }
#undef CONV_STAGE

  // epilogue: bias/relu/stats; acc -> swizzled LDS C-tile [128 l][256 o];
  // full-line 512 B coalesced blast (no partial-line L2 write-allocate).
  float cs[4][4] = {{0.f}}, cq[4][4] = {{0.f}};
  #pragma unroll
  for (int m = 0; m < 4; ++m){
    const int col = wr*64 + m*16 + g*4;                  // output channel o
    float bi[4] = {0.f, 0.f, 0.f, 0.f};
    if (bias){
      const f32x4 bv = *reinterpret_cast<const f32x4*>(bias + b*256 + col);
      bi[0]=bv[0]; bi[1]=bv[1]; bi[2]=bv[2]; bi[3]=bv[3];
    }
    #pragma unroll
    for (int n = 0; n < 4; ++n){
      const int row = wc*64 + n*16 + frow;               // l in [0,128)
      float v[4];
      #pragma unroll
      for (int j = 0; j < 4; ++j){
        v[j] = acc[m][n][j] + bi[j];
        if (applyRelu) v[j] = fmaxf(v[j], 0.f);
        cs[m][j] += v[j];
        cq[m][j] += v[j]*v[j];
      }
      uint2v pk;
      pk[0] = (unsigned)f2b(v[0]) | ((unsigned)f2b(v[1]) << 16);
      pk[1] = (unsigned)f2b(v[2]) | ((unsigned)f2b(v[3]) << 16);
      const int chunk = (col >> 3) ^ (row & 31);
      *reinterpret_cast<uint2v*>((char*)sAll + row*512 + chunk*16 + (g&1)*8) = pk;
    }
  }
  __syncthreads();
  {
    char* gp = (char*)out + 2*((size_t)b*outBatchStride + (size_t)(l0 + outRowOff)*256);
    #pragma unroll
    for (int it = 0; it < 8; ++it){
      const int row = it*16 + (tid >> 5);
      const int c = tid & 31;
      const int cs2 = c ^ (row & 31);
      const uint4v v = *reinterpret_cast<const uint4v*>((const char*)sAll + row*512 + cs2*16);
      *reinterpret_cast<uint4v*>(gp + (size_t)row*512 + c*16) = v;
    }
  }
  if (statSum){
    #pragma unroll
    for (int m = 0; m < 4; ++m)
      #pragma unroll
      for (int j = 0; j < 4; ++j){
        #pragma unroll
        for (int d = 1; d < 16; d <<= 1){
          cs[m][j] += __shfl_xor(cs[m][j], d);
          cq[m][j] += __shfl_xor(cq[m][j], d);
        }
      }
    __syncthreads();                       // blast reads done -> LDS reusable
    float* ls = (float*)sAll;              // [8 waves][64 ch]
    float* lq = ls + 512;
    if (frow == 0){
      #pragma unroll
      for (int m = 0; m < 4; ++m)
        #pragma unroll
        for (int j = 0; j < 4; ++j){
          ls[wid*64 + m*16 + g*4 + j] = cs[m][j];
          lq[wid*64 + m*16 + g*4 + j] = cq[m][j];
        }
    }
    __syncthreads();
    if (tid < 256){
      const int o = tid, wrI = o >> 6, idx = o & 63;
      const float s  = ls[(wrI*2 + 0)*64 + idx] + ls[(wrI*2 + 1)*64 + idx];
      const float qq = lq[(wrI*2 + 0)*64 + idx] + lq[(wrI*2 + 1)*64 + idx];
      atomicAdd(statSum + o, s);
      atomicAdd(statSq  + o, qq);
    }
  }
}

__global__ void k_bnfin(const float* __restrict__ sum, const float* __restrict__ sq,
                        const float* __restrict__ g, const float* __restrict__ bb,
                        float* __restrict__ scale, float* __restrict__ shift)
{
  const int o = threadIdx.x;
  const float inv = 1.f/65536.f;
  const float m = sum[o]*inv;
  const float v = fmaxf(sq[o]*inv - m*m, 0.f);
  const float sc = g[o] / sqrtf(v + 1e-5f);
  scale[o] = sc;
  shift[o] = bb[o] - m*sc;
}

// ---- h2T[b][lp][o] = relu(y2T[b][lp-1][o]*scale+shift), pads zeroed ----
__global__ __launch_bounds__(256) void k_norm2(const bf16* __restrict__ y, const float* __restrict__ scale,
                                               const float* __restrict__ shift, bf16* __restrict__ h)
{
  const int gr = blockIdx.x*8 + (threadIdx.x >> 5);
  const int oc = threadIdx.x & 31;
  const int b = gr / 4098, lp = gr - b*4098;
  unsigned short* dst = (unsigned short*)h + (size_t)gr*256 + oc*8;
  if (lp == 0 || lp == 4097){
    uint4v z = {0u,0u,0u,0u};
    *reinterpret_cast<uint4v*>(dst) = z;
    return;
  }
  const unsigned short* src = (const unsigned short*)y + ((size_t)b*4096 + (lp-1))*256 + oc*8;
  const uint4v in = *reinterpret_cast<const uint4v*>(src);
  const f32x4 sA0 = *reinterpret_cast<const f32x4*>(scale + oc*8);
  const f32x4 sA1 = *reinterpret_cast<const f32x4*>(scale + oc*8 + 4);
  const f32x4 hA0 = *reinterpret_cast<const f32x4*>(shift + oc*8);
  const f32x4 hA1 = *reinterpret_cast<const f32x4*>(shift + oc*8 + 4);
  uint4v ov;
  #pragma unroll
  for (int e = 0; e < 4; ++e){
    const unsigned int w = in[e];
    const float sc0 = (e<2) ? sA0[2*e] : sA1[2*e-4];
    const float sc1 = (e<2) ? sA0[2*e+1] : sA1[2*e-3];
    const float sh0 = (e<2) ? hA0[2*e] : hA1[2*e-4];
    const float sh1 = (e<2) ? hA0[2*e+1] : hA1[2*e-3];
    const float v0 = fmaxf(b2f((unsigned short)(w & 0xffffu))*sc0 + sh0, 0.f);
    const float v1 = fmaxf(b2f((unsigned short)(w >> 16))*sc1 + sh1, 0.f);
    ov[e] = (unsigned)f2b(v0) | ((unsigned)f2b(v1) << 16);
  }
  *reinterpret_cast<uint4v*>(dst) = ov;
}

// ---- h3 = relu(y3*scale+shift) in-place, plus per-(b,o) sums for SE ----
__global__ __launch_bounds__(256) void k_norm3(bf16* __restrict__ y, const float* __restrict__ scale,
                                               const float* __restrict__ shift, float* __restrict__ s_sum)
{
  __shared__ float red[8][256];
  const int tid = threadIdx.x;
  const int rr = tid >> 5, oc = tid & 31;
  const size_t row = (size_t)blockIdx.x*8 + rr;
  const int b = (int)(row >> 12);
  unsigned short* p = (unsigned short*)y + row*256 + oc*8;
  const uint4v in = *reinterpret_cast<const uint4v*>(p);
  const f32x4 sA0 = *reinterpret_cast<const f32x4*>(scale + oc*8);
  const f32x4 sA1 = *reinterpret_cast<const f32x4*>(scale + oc*8 + 4);
  const f32x4 hA0 = *reinterpret_cast<const f32x4*>(shift + oc*8);
  const f32x4 hA1 = *reinterpret_cast<const f32x4*>(shift + oc*8 + 4);
  uint4v ov;
  float loc[8];
  #pragma unroll
  for (int e = 0; e < 4; ++e){
    const unsigned int w = in[e];
    const float sc0 = (e<2) ? sA0[2*e] : sA1[2*e-4];
    const float sc1 = (e<2) ? sA0[2*e+1] : sA1[2*e-3];
    const float sh0 = (e<2) ? hA0[2*e] : hA1[2*e-4];
    const float sh1 = (e<2) ? hA0[2*e+1] : hA1[2*e-3];
    const float v0 = fmaxf(b2f((unsigned short)(w & 0xffffu))*sc0 + sh0, 0.f);
    const float v1 = fmaxf(b2f((unsigned short)(w >> 16))*sc1 + sh1, 0.f);
    loc[2*e] = v0; loc[2*e+1] = v1;
    ov[e] = (unsigned)f2b(v0) | ((unsigned)f2b(v1) << 16);
  }
  *reinterpret_cast<uint4v*>(p) = ov;
  #pragma unroll
  for (int j = 0; j < 8; ++j) red[rr][oc*8 + j] = loc[j];
  __syncthreads();
  const int o = tid;
  float tot = 0.f;
  #pragma unroll
  for (int r2 = 0; r2 < 8; ++r2) tot += red[r2][o];
  atomicAdd(&s_sum[(size_t)b*256 + o], tot);
}

// ---- SE: s2[b][o] = sigmoid(W2 @ relu(W1 @ mean + b1) + b2) ----
__global__ __launch_bounds__(256) void k_se(const float* __restrict__ s_sum, const float* __restrict__ w1,
                                            const float* __restrict__ b1, const float* __restrict__ w2,
                                            const float* __restrict__ b2, float* __restrict__ s2)
{
  __shared__ float sv[256];
  __shared__ float t1[256];
  const int b = blockIdx.x, o = threadIdx.x;
  sv[o] = s_sum[(size_t)b*256 + o] * (1.f/4096.f);
  __syncthreads();
  float a = b1[o];
  for (int c = 0; c < 256; ++c) a += w1[(size_t)o*256 + c] * sv[c];
  t1[o] = fmaxf(a, 0.f);
  __syncthreads();
  float a2 = b2[o];
  for (int c = 0; c < 256; ++c) a2 += w2[(size_t)o*256 + c] * t1[c];
  s2[(size_t)b*256 + o] = 1.f / (1.f + expf(-a2));
}

// ---- out[b][o][l] = relu(h3T[b][l][o]*s2[b][o] + x[b][o][l]) ----
__global__ __launch_bounds__(256) void k_final(const bf16* __restrict__ h3, const float* __restrict__ s2,
                                               const float* __restrict__ x, float* __restrict__ out)
{
  __shared__ float tile[64][65];
  const int b = blockIdx.z, o0 = blockIdx.y*64, l0 = blockIdx.x*64;
  const int tid = threadIdx.x;
  {
    const int r = tid >> 2, q = tid & 3;
    const unsigned short* src = (const unsigned short*)h3 + ((size_t)b*4096 + l0 + r)*256 + o0 + q*16;
    const uint4v a0 = *reinterpret_cast<const uint4v*>(src);
    const uint4v a1 = *reinterpret_cast<const uint4v*>(src + 8);
    #pragma unroll
    for (int e = 0; e < 4; ++e){
      tile[r][q*16 + 2*e]         = b2f((unsigned short)(a0[e] & 0xffffu));
      tile[r][q*16 + 2*e + 1]     = b2f((unsigned short)(a0[e] >> 16));
      tile[r][q*16 + 8 + 2*e]     = b2f((unsigned short)(a1[e] & 0xffffu));
      tile[r][q*16 + 8 + 2*e + 1] = b2f((unsigned short)(a1[e] >> 16));
    }
  }
  __syncthreads();
  {
    const int orow = tid >> 2, q = tid & 3;
    const int o = o0 + orow;
    const float sc = s2[(size_t)b*256 + o];
    const float* xs = x + ((size_t)b*256 + o)*4096 + l0 + q*16;
    float* dst = out + ((size_t)b*256 + o)*4096 + l0 + q*16;
    #pragma unroll
    for (int k = 0; k < 16; k += 4){
      const f32x4 xv = *reinterpret_cast<const f32x4*>(xs + k);
      f32x4 r;
      #pragma unroll
      for (int e = 0; e < 4; ++e)
        r[e] = fmaxf(tile[q*16 + k + e][orow]*sc + xv[e], 0.f);
      *reinterpret_cast<f32x4*>(dst + k) = r;
    }
  }
}

extern "C" void kernel_launch(void* const* d_in, const int* in_sizes, int n_in,
                              void* d_out, int out_size, void* d_ws, size_t ws_size,
                              hipStream_t stream)
{
  const float* x     = (const float*)d_in[0];
  const float* att1  = (const float*)d_in[1];
  const float* att2  = (const float*)d_in[2];
  const float* att3  = (const float*)d_in[3];
  const float* w1_w  = (const float*)d_in[4];
  const float* w1_b  = (const float*)d_in[5];
  const float* w2_w  = (const float*)d_in[6];
  const float* w2_b  = (const float*)d_in[7];
  const float* w3_w  = (const float*)d_in[8];
  const float* w3_b  = (const float*)d_in[9];
  const float* b1_w  = (const float*)d_in[10];
  const float* b1_b  = (const float*)d_in[11];
  const float* bn2_w = (const float*)d_in[12];
  const float* bn2_b = (const float*)d_in[13];
  const float* bn3_w = (const float*)d_in[14];
  const float* bn3_b = (const float*)d_in[15];
  const float* se1_w = (const float*)d_in[16];
  const float* se1_b = (const float*)d_in[17];
  const float* se2_w = (const float*)d_in[18];
  const float* se2_b = (const float*)d_in[19];

  char* ws = (char*)d_ws;
  // workspace layout (bytes)
  bf16*  xT   = (bf16*)(ws + 0);           // [16][4098][256]  (reused as y3T/h3T)
  bf16*  h1T  = (bf16*)(ws + 33570816);    // [16][4098][256]
  bf16*  y2T  = (bf16*)(ws + 67141632);    // [16][4096][256]
  bf16*  h2T  = (bf16*)(ws + 100696064);   // [16][4098][256]
  bf16*  Wt   = (bf16*)(ws + 134266880);   // [3][16][3][256][256]
  bf16*  wb   = (bf16*)(ws + 178307072);   // [3][768][1024]
  float* b1v  = (float*)(ws + 183025664);  // [4096]
  float* st   = (float*)(ws + 183042048);
  float* bn2sum = st;          // 256
  float* bn2sq  = st + 256;
  float* bn3sum = st + 512;
  float* bn3sq  = st + 768;
  float* s_sum  = st + 1024;   // 4096
  float* scale2 = st + 5120;
  float* shift2 = st + 5376;
  float* scale3 = st + 5632;
  float* shift3 = st + 5888;
  float* s2v    = st + 6144;   // 4096
  bf16*  y3T  = (bf16*)(ws + 0);           // overlay on xT (dead after conv1)

  // zero accumulators (bn2/bn3 sums + s_sum = 5120 floats)
  hipMemsetAsync(st, 0, 5120*sizeof(float), stream);

  k_transpose_x<<<dim3(64,4,16),256,0,stream>>>(x, xT);
  k_zero_pads<<<16,256,0,stream>>>(xT, h1T);
  k_cvt3<<<512,256,0,stream>>>(w1_w, w2_w, w3_w, wb, 768*1024);
  k_gen<<<dim3(64,1,9),256,0,stream>>>(att1, att2, att3, wb, w1_b, w2_b, w3_b, Wt);
  k_b1<<<1024,256,0,stream>>>(att1, b1_w, b1_b, b1v);

  k_conv<<<dim3(32,1,16),512,0,stream>>>(xT,  Wt,                           b1v,     h1T, 4098*256, 1, 1, nullptr, nullptr);
  k_conv<<<dim3(32,1,16),512,0,stream>>>(h1T, Wt + (size_t)1*16*3*256*256,  nullptr, y2T, 4096*256, 0, 0, bn2sum, bn2sq);
  k_bnfin<<<1,256,0,stream>>>(bn2sum, bn2sq, bn2_w, bn2_b, scale2, shift2);
  k_norm2<<<8196,256,0,stream>>>(y2T, scale2, shift2, h2T);
  k_conv<<<dim3(32,1,16),512,0,stream>>>(h2T, Wt + (size_t)2*16*3*256*256,  nullptr, y3T, 4096*256, 0, 0, bn3sum, bn3sq);
  k_bnfin<<<1,256,0,stream>>>(bn3sum, bn3sq, bn3_w, bn3_b, scale3, shift3);
  k_norm3<<<8192,256,0,stream>>>(y3T, scale3, shift3, s_sum);
  k_se<<<16,256,0,stream>>>(s_sum, se1_w, se1_b, se2_w, se2_b, s2v);
  k_final<<<dim3(64,4,16),256,0,stream>>>((const bf16*)y3T, s2v, x, (float*)d_out);
}